// Round 4
// baseline (5072.893 us; speedup 1.0000x reference)
//
#include <hip/hip_runtime.h>
#include <hip/hip_bf16.h>

// ViT-S/16 forward, B=128. Inputs/outputs fp32 (per reference). Internal:
// weights+activations bf16 for MFMA, residual stream fp32, LN/softmax fp32.
// R5: k_gemm = double-buffered LDS (one barrier/iter) + XOR chunk-swizzle.
// R6 (atomic split-K) and R7 (BM=64 split-M) both regressed -> reverted to
// R5 tiling (BM=128, grid (N/128, M/128)).
// R8: LayerNorm fused into the consuming GEMM (qkv, fc1). gamma is folded
// into the bf16 weight conversion (W*g columnwise), beta into the GEMM bias
// (bias + b.W^T, small precompute). The GEMM reads the fp32 residual h
// directly: per-block row-stats prepass, then (x-mean)*rstd normalization
// applied while staging A into LDS. Deletes all 24 k_ln dispatches and the
// xn buffer round-trip (~80 MB/layer less HBM traffic).
// R9: identical resubmit of R8 (previous bench died to a container/infra
// failure, not a kernel error; audit found no OOB/barrier/LDS hazard).

#define S_ 197
#define D_ 384
#define BATCH 128

using bf16 = __hip_bfloat16;
typedef __attribute__((ext_vector_type(8))) __bf16 bf16x8;
typedef __attribute__((ext_vector_type(4))) float f32x4;

#if __has_builtin(__builtin_amdgcn_global_load_lds)
#define HAVE_GLL 1
__device__ __forceinline__ void gll16(const bf16* g, __bf16* l) {
  __builtin_amdgcn_global_load_lds(
      (const __attribute__((address_space(1))) void*)g,
      (__attribute__((address_space(3))) void*)l, 16, 0, 0);
}
#else
#define HAVE_GLL 0
#endif

// fp32 -> bf16 (RN), 4 elements/thread. n must be a multiple of 4.
__global__ __launch_bounds__(256) void k_f2b(const float* __restrict__ src,
                                             bf16* __restrict__ dst, int n4) {
  int i = blockIdx.x * 256 + threadIdx.x;
  if (i >= n4) return;
  float4 v = ((const float4*)src)[i];
  bf16 o[4] = {__float2bfloat16(v.x), __float2bfloat16(v.y),
               __float2bfloat16(v.z), __float2bfloat16(v.w)};
  ((uint2*)dst)[i] = *(uint2*)o;
}

// fp32 -> bf16 with columnwise LN-gamma fold: dst = bf16(src * g[layer][col]).
// W layout [12][rowsPerLayer][384]; col = elem % 384.
__global__ __launch_bounds__(256) void k_f2b_g(const float* __restrict__ src,
                                               const float* __restrict__ g,
                                               bf16* __restrict__ dst, int n4,
                                               int rowsPerLayer) {
  int i = blockIdx.x * 256 + threadIdx.x;
  if (i >= n4) return;
  size_t base = (size_t)i * 4;
  int col = (int)(base % 384);
  int layer = (int)(base / ((size_t)rowsPerLayer * 384));
  float4 v = ((const float4*)src)[i];
  float4 gg = *(const float4*)(g + (size_t)layer * 384 + col);
  bf16 o[4] = {__float2bfloat16(v.x * gg.x), __float2bfloat16(v.y * gg.y),
               __float2bfloat16(v.z * gg.z), __float2bfloat16(v.w * gg.w)};
  ((uint2*)dst)[i] = *(uint2*)o;
}

// LN-beta fold into bias: outb[l][n] = base[l][n] + sum_k lnb[l][k]*W[l][n][k]
__global__ __launch_bounds__(256) void k_biasfold(const float* __restrict__ W,
                                                  const float* __restrict__ lnb,
                                                  const float* __restrict__ base,
                                                  float* __restrict__ outb,
                                                  int rowsPerLayer) {
  int n = blockIdx.x * 256 + threadIdx.x;
  if (n >= 12 * rowsPerLayer) return;
  int layer = n / rowsPerLayer, r = n % rowsPerLayer;
  const float* wr = W + ((size_t)layer * rowsPerLayer + r) * 384;
  const float* bb = lnb + (size_t)layer * 384;
  float a = base[n];
  for (int k = 0; k < 384; k += 4) {
    float4 wv = *(const float4*)(wr + k);
    float4 bv = *(const float4*)(bb + k);
    a += wv.x * bv.x + wv.y * bv.y + wv.z * bv.z + wv.w * bv.w;
  }
  outb[n] = a;
}

__global__ __launch_bounds__(256) void k_embed_init(const float* __restrict__ cls,
                                                    const float* __restrict__ pos,
                                                    float* __restrict__ h) {
  int idx = blockIdx.x * 256 + threadIdx.x;
  if (idx >= BATCH * S_ * D_) return;
  int d = idx % D_;
  int s = (idx / D_) % S_;
  float v = pos[s * D_ + d];
  if (s == 0) v += cls[d];
  h[idx] = v;
}

__global__ __launch_bounds__(256) void k_patchify(const float* __restrict__ x,
                                                  bf16* __restrict__ patches) {
  int idx = blockIdx.x * 256 + threadIdx.x;
  if (idx >= BATCH * 196 * 768) return;
  int f = idx % 768;
  int n = (idx / 768) % 196;
  int b = idx / (768 * 196);
  int c = f >> 8, rem = f & 255, dy = rem >> 4, dx = rem & 15;
  int py = n / 14, px = n % 14;
  patches[idx] = __float2bfloat16(
      x[(((size_t)b * 3 + c) * 224 + py * 16 + dy) * 224 + px * 16 + dx]);
}

// out[M,N] = A[M,K] @ W[N,K]^T + bias.  Grid: (N/128, M/128), 256 threads.
// MODE 0: out=bf16(v); MODE 1: out=bf16(gelu_exact(v)); MODE 2: res(f32)+=v
// LNF 1: A-operand is LayerNorm'd fp32 residual Xf (gamma/beta pre-folded
//        into W/bias): per-block row stats prepass, normalize while staging.
//        Requires K==384, M tiles with no tail (M = 128*gridDim.y).
// remap!=0 (patch embed): residual row = r + r/196 + 1
// LDS layout: row stride 32 elems (64B), 4 chunks of 8 elems per row; slot
// chunk j holds global chunk j ^ ((row>>1)&3)  -> b128 frag reads are 2-way
// bank-aliased (free). Double-buffered: prefetch k+1 while computing k.
template <int MODE, int LNF>
__global__ __launch_bounds__(256, 4) void k_gemm(
    const bf16* __restrict__ X, const bf16* __restrict__ W,
    const float* __restrict__ bias, bf16* __restrict__ out,
    float* __restrict__ res, const float* __restrict__ Xf,
    int N, int K, int remap) {
  __shared__ __align__(16) __bf16 As[2][128 * 32];
  __shared__ __align__(16) __bf16 Bs[2][128 * 32];
  __shared__ float smean[128], srstd[128];
  const int tid = threadIdx.x;
  const int m0 = blockIdx.y * 128, n0 = blockIdx.x * 128;
  const int lane = tid & 63, w = tid >> 6;
  const int wr = w >> 1, wc = w & 1;
  const int l16 = lane & 15, quad = lane >> 4;
  f32x4 acc[4][4] = {};

  // staging: wave w covers tile rows w*32..w*32+31; lane -> slot row
  // (lane>>2), slot chunk (lane&3); global chunk swizzled:
  // c = (lane&3) ^ ((lane>>3)&3)
  const int srow = w * 32 + (lane >> 2);
  const int scol = (((lane & 3) ^ ((lane >> 3) & 3)) << 3);
  const bf16* Ag = LNF ? nullptr : X + (size_t)(m0 + srow) * K + scol;
  const bf16* Bg = W + (size_t)(n0 + srow) * K + scol;
  const int ldsW = w * 32 * 32;  // wave-uniform LDS base offset (elems)

  const float* hA = nullptr;
  float mA0 = 0.f, rA0 = 0.f, mA1 = 0.f, rA1 = 0.f;
  if constexpr (LNF) {
    // row-stats prepass: wave w handles rows w*32..w*32+31; 8 lanes/row,
    // 48 contiguous cols/lane (K==384).
    for (int rr = 0; rr < 4; rr++) {
      const int r = w * 32 + rr * 8 + (lane >> 3);
      const float* hr = Xf + (size_t)(m0 + r) * 384 + (lane & 7) * 48;
      float s = 0.f, q = 0.f;
#pragma unroll
      for (int c = 0; c < 12; c++) {
        float4 v = ((const float4*)hr)[c];
        s += v.x + v.y + v.z + v.w;
        q += v.x * v.x + v.y * v.y + v.z * v.z + v.w * v.w;
      }
#pragma unroll
      for (int o = 1; o < 8; o <<= 1) {
        s += __shfl_xor(s, o);
        q += __shfl_xor(q, o);
      }
      if ((lane & 7) == 0) {
        float m = s * (1.f / 384.f);
        smean[r] = m;
        srstd[r] = rsqrtf(q * (1.f / 384.f) - m * m + 1e-5f);
      }
    }
    __syncthreads();
    hA = Xf + (size_t)(m0 + srow) * 384 + scol;
    mA0 = smean[srow];      rA0 = srstd[srow];
    mA1 = smean[srow + 16]; rA1 = srstd[srow + 16];
  }

  // fragment read offsets: row r needs global chunk `quad`, stored at slot
  // chunk quad ^ ((l16>>1)&3)
  const int jx8 = ((quad ^ ((l16 >> 1) & 3)) << 3);
  const int aoff = (wr * 64 + l16) * 32 + jx8;
  const int boff = (wc * 64 + l16) * 32 + jx8;

  auto stageA_ln = [&](int buf, int k0) {
    float4 u0 = *(const float4*)(hA + k0);
    float4 u1 = *(const float4*)(hA + k0 + 4);
    float4 v0 = *(const float4*)(hA + 16 * 384 + k0);
    float4 v1 = *(const float4*)(hA + 16 * 384 + k0 + 4);
    bf16 t0[8] = {__float2bfloat16((u0.x - mA0) * rA0),
                  __float2bfloat16((u0.y - mA0) * rA0),
                  __float2bfloat16((u0.z - mA0) * rA0),
                  __float2bfloat16((u0.w - mA0) * rA0),
                  __float2bfloat16((u1.x - mA0) * rA0),
                  __float2bfloat16((u1.y - mA0) * rA0),
                  __float2bfloat16((u1.z - mA0) * rA0),
                  __float2bfloat16((u1.w - mA0) * rA0)};
    bf16 t1[8] = {__float2bfloat16((v0.x - mA1) * rA1),
                  __float2bfloat16((v0.y - mA1) * rA1),
                  __float2bfloat16((v0.z - mA1) * rA1),
                  __float2bfloat16((v0.w - mA1) * rA1),
                  __float2bfloat16((v1.x - mA1) * rA1),
                  __float2bfloat16((v1.y - mA1) * rA1),
                  __float2bfloat16((v1.z - mA1) * rA1),
                  __float2bfloat16((v1.w - mA1) * rA1)};
    *(uint4*)(&As[buf][ldsW + (lane >> 2) * 32 + (lane & 3) * 8]) = *(uint4*)t0;
    *(uint4*)(&As[buf][ldsW + 512 + (lane >> 2) * 32 + (lane & 3) * 8]) = *(uint4*)t1;
  };

#if HAVE_GLL
#define STAGE(buf, k0)                                           \
  do {                                                           \
    if constexpr (LNF) {                                         \
      stageA_ln(buf, k0);                                        \
    } else {                                                     \
      gll16(Ag + (k0), &As[buf][ldsW]);                          \
      gll16(Ag + (k0) + (size_t)16 * K, &As[buf][ldsW + 512]);   \
    }                                                            \
    gll16(Bg + (k0), &Bs[buf][ldsW]);                            \
    gll16(Bg + (k0) + (size_t)16 * K, &Bs[buf][ldsW + 512]);     \
  } while (0)
#else
#define STAGE(buf, k0)                                                        \
  do {                                                                        \
    if constexpr (LNF) {                                                      \
      stageA_ln(buf, k0);                                                     \
    } else {                                                                  \
      *(uint4*)(&As[buf][ldsW + (lane >> 2) * 32 + (lane & 3) * 8]) =         \
          *(const uint4*)(Ag + (k0));                                         \
      *(uint4*)(&As[buf][ldsW + 512 + (lane >> 2) * 32 + (lane & 3) * 8]) =   \
          *(const uint4*)(Ag + (k0) + (size_t)16 * K);                        \
    }                                                                         \
    *(uint4*)(&Bs[buf][ldsW + (lane >> 2) * 32 + (lane & 3) * 8]) =           \
        *(const uint4*)(Bg + (k0));                                           \
    *(uint4*)(&Bs[buf][ldsW + 512 + (lane >> 2) * 32 + (lane & 3) * 8]) =     \
        *(const uint4*)(Bg + (k0) + (size_t)16 * K);                          \
  } while (0)
#endif

  STAGE(0, 0);
  __syncthreads();
  for (int k0 = 0; k0 < K; k0 += 32) {
    const int cb = (k0 >> 5) & 1;
    if (k0 + 32 < K) STAGE(cb ^ 1, k0 + 32);
    bf16x8 av[4], bv[4];
#pragma unroll
    for (int i = 0; i < 4; i++)
      av[i] = *(const bf16x8*)(&As[cb][aoff + i * 512]);
#pragma unroll
    for (int j = 0; j < 4; j++)
      bv[j] = *(const bf16x8*)(&Bs[cb][boff + j * 512]);
#pragma unroll
    for (int i = 0; i < 4; i++)
#pragma unroll
      for (int j = 0; j < 4; j++)
        acc[i][j] = __builtin_amdgcn_mfma_f32_16x16x32_bf16(av[i], bv[j], acc[i][j], 0, 0, 0);
    __syncthreads();
  }
#undef STAGE

  float bvv[4];
#pragma unroll
  for (int j = 0; j < 4; j++)
    bvv[j] = bias[n0 + wc * 64 + j * 16 + l16];
#pragma unroll
  for (int i = 0; i < 4; i++) {
    const int rbase = m0 + wr * 64 + i * 16 + quad * 4;
#pragma unroll
    for (int j = 0; j < 4; j++) {
      const int col = n0 + wc * 64 + j * 16 + l16;
#pragma unroll
      for (int r = 0; r < 4; r++) {
        float v = acc[i][j][r] + bvv[j];
        int rw = rbase + r;
        if (MODE == 0) {
          out[(size_t)rw * N + col] = __float2bfloat16(v);
        } else if (MODE == 1) {
          float gl = 0.5f * v * (1.f + erff(v * 0.70710678118f));
          out[(size_t)rw * N + col] = __float2bfloat16(gl);
        } else {
          int hr = remap ? (rw + rw / 196 + 1) : rw;
          res[(size_t)hr * N + col] += v;
        }
      }
    }
  }
}

// MFMA flash attention. One block per (b, head), 4 waves. Each wave owns
// q-bands {w, w+4, w+8, ...} of 16 rows: QK^T (13 col-tiles, K=64) -> masked
// softmax (band-local, shuffle over l16 only) -> P band to LDS (C->A layout
// round-trip) -> P@V via LDS V^T. No __syncthreads after staging.
__global__ __launch_bounds__(256) void k_attn(const bf16* __restrict__ qkv,
                                              bf16* __restrict__ ctx) {
  const int bh = blockIdx.x;
  const int b = bh / 6, hd = bh % 6;
  const bf16* Qg = qkv + (size_t)b * S_ * 1152 + hd * 64;
  const bf16* Kg = Qg + 384;
  const bf16* Vg = Qg + 768;
  // Vt[d][k] = V[k][d]; stride 232 (116 dw -> 2-way bank alias = free)
  __shared__ __align__(16) __bf16 Vt[64 * 232];
  __shared__ __align__(16) __bf16 Ps[4][16 * 232];
  const int tid = threadIdx.x;
  const int lane = tid & 63, w = tid >> 6;
  const int l16 = lane & 15, quad = lane >> 4;
  const __bf16 z = (__bf16)0.0f;

  // zero Vt pad cols (k = 197..231)
  for (int i = tid; i < 64 * 35; i += 256) {
    int d = i / 35, k = 197 + i % 35;
    Vt[d * 232 + k] = z;
  }
  // stage V transposed
  for (int i = tid; i < S_ * 64; i += 256) {
    int k = i >> 6, d = i & 63;
    Vt[d * 232 + k] = *(const __bf16*)&Vg[(size_t)k * 1152 + d];
  }
  // zero own Ps pad cols (208..231)
  for (int i = lane; i < 16 * 24; i += 64) {
    int r = i / 24, c = 208 + i % 24;
    Ps[w][r * 232 + c] = z;
  }
  __syncthreads();

  const bf16x8 zf = {};
  for (int band = w; band < 13; band += 4) {
    // Q A-fragments (row = band*16 + l16), predicated on row < 197
    const int qrow = band * 16 + l16;
    bf16x8 aq0 = zf, aq1 = zf;
    if (qrow < S_) {
      aq0 = *(const bf16x8*)(Qg + (size_t)qrow * 1152 + quad * 8);
      aq1 = *(const bf16x8*)(Qg + (size_t)qrow * 1152 + 32 + quad * 8);
    }
    // scores: 13 col-tiles of 16
    f32x4 sc[13];
#pragma unroll
    for (int t = 0; t < 13; t++) {
      const int krow = t * 16 + l16;
      bf16x8 bk0 = zf, bk1 = zf;
      if (krow < S_) {
        bk0 = *(const bf16x8*)(Kg + (size_t)krow * 1152 + quad * 8);
        bk1 = *(const bf16x8*)(Kg + (size_t)krow * 1152 + 32 + quad * 8);
      }
      f32x4 a = {};
      a = __builtin_amdgcn_mfma_f32_16x16x32_bf16(aq0, bk0, a, 0, 0, 0);
      a = __builtin_amdgcn_mfma_f32_16x16x32_bf16(aq1, bk1, a, 0, 0, 0);
      sc[t] = a;
    }
    // scale 1/sqrt(64), mask pad cols (192+l16 >= 197)
#pragma unroll
    for (int t = 0; t < 13; t++)
#pragma unroll
      for (int r = 0; r < 4; r++) sc[t][r] *= 0.125f;
    if (l16 >= 5) {
#pragma unroll
      for (int r = 0; r < 4; r++) sc[12][r] = -1e30f;
    }
    // row max (across 13 tiles in-reg, then across the 16 lanes of this quad)
    f32x4 mx = sc[0];
#pragma unroll
    for (int t = 1; t < 13; t++)
#pragma unroll
      for (int r = 0; r < 4; r++) mx[r] = fmaxf(mx[r], sc[t][r]);
#pragma unroll
    for (int o = 1; o < 16; o <<= 1)
#pragma unroll
      for (int r = 0; r < 4; r++) mx[r] = fmaxf(mx[r], __shfl_xor(mx[r], o));
    // exp + row sum
    f32x4 sum = {};
#pragma unroll
    for (int t = 0; t < 13; t++)
#pragma unroll
      for (int r = 0; r < 4; r++) {
        float p = __expf(sc[t][r] - mx[r]);
        sc[t][r] = p;
        sum[r] += p;
      }
#pragma unroll
    for (int o = 1; o < 16; o <<= 1)
#pragma unroll
      for (int r = 0; r < 4; r++) sum[r] += __shfl_xor(sum[r], o);
    f32x4 rinv;
#pragma unroll
    for (int r = 0; r < 4; r++) rinv[r] = 1.0f / sum[r];
    // write unnormalized P band (C layout -> LDS); pad cols 197..207 are
    // exact zeros (exp(-1e30-m) underflows to 0)
#pragma unroll
    for (int t = 0; t < 13; t++)
#pragma unroll
      for (int r = 0; r < 4; r++)
        Ps[w][(quad * 4 + r) * 232 + t * 16 + l16] = (__bf16)sc[t][r];
    // P @ V: out cols d = c*16 + l16, k over 224 (7 steps of 32)
    f32x4 oacc[4] = {};
#pragma unroll
    for (int ks = 0; ks < 7; ks++) {
      bf16x8 pa = *(const bf16x8*)&Ps[w][l16 * 232 + ks * 32 + quad * 8];
#pragma unroll
      for (int c = 0; c < 4; c++) {
        bf16x8 bv = *(const bf16x8*)&Vt[(c * 16 + l16) * 232 + ks * 32 + quad * 8];
        oacc[c] = __builtin_amdgcn_mfma_f32_16x16x32_bf16(pa, bv, oacc[c], 0, 0, 0);
      }
    }
    // epilogue: rows band*16 + quad*4 + r (guarded), cols hd*64 + c*16 + l16
    const int orow = band * 16 + quad * 4;
#pragma unroll
    for (int c = 0; c < 4; c++)
#pragma unroll
      for (int r = 0; r < 4; r++) {
        const int rw = orow + r;
        if (rw < S_)
          ctx[((size_t)b * S_ + rw) * D_ + hd * 64 + c * 16 + l16] =
              __float2bfloat16(oacc[c][r] * rinv[r]);
      }
  }
}

__global__ __launch_bounds__(128) void k_head(const float* __restrict__ h,
                                              const float* __restrict__ g,
                                              const float* __restrict__ bt,
                                              const float* __restrict__ hw,
                                              float* __restrict__ out) {
  const int b = blockIdx.x, t = threadIdx.x;
  const float* row = h + (size_t)b * S_ * D_;
  float x0 = row[t], x1 = row[t + 128], x2 = row[t + 256];
  float s = x0 + x1 + x2;
  float q = x0 * x0 + x1 * x1 + x2 * x2;
#pragma unroll
  for (int o = 32; o; o >>= 1) {
    s += __shfl_xor(s, o);
    q += __shfl_xor(q, o);
  }
  __shared__ float rs[2], rq[2];
  if ((t & 63) == 0) { rs[t >> 6] = s; rq[t >> 6] = q; }
  __syncthreads();
  s = rs[0] + rs[1];
  q = rq[0] + rq[1];
  const float mean = s * (1.f / 384.f);
  const float var = q * (1.f / 384.f) - mean * mean;
  const float rstd = rsqrtf(var + 1e-5f);
  __shared__ float clsn[384];
  clsn[t] = (x0 - mean) * rstd * g[t] + bt[t];
  clsn[t + 128] = (x1 - mean) * rstd * g[t + 128] + bt[t + 128];
  clsn[t + 256] = (x2 - mean) * rstd * g[t + 256] + bt[t + 256];
  __syncthreads();
  if (t < 100) {
    const float* wr = hw + (size_t)t * D_;
    float a = 0.f;
    for (int d = 0; d < 384; d++) a += clsn[d] * wr[d];
    out[b * 100 + t] = a;
  }
}

extern "C" void kernel_launch(void* const* d_in, const int* in_sizes, int n_in,
                              void* d_out, int out_size, void* d_ws, size_t ws_size,
                              hipStream_t stream) {
  (void)in_sizes; (void)n_in; (void)out_size; (void)ws_size;
  const float* x       = (const float*)d_in[0];
  const float* patch_w = (const float*)d_in[1];
  const float* patch_b = (const float*)d_in[2];
  const float* cls_tok = (const float*)d_in[3];
  const float* pos_emb = (const float*)d_in[4];
  const float* ln1_g   = (const float*)d_in[5];
  const float* ln1_b   = (const float*)d_in[6];
  const float* qkv_w   = (const float*)d_in[7];
  const float* qkv_b   = (const float*)d_in[8];
  const float* out_w   = (const float*)d_in[9];
  const float* out_b   = (const float*)d_in[10];
  const float* ln2_g   = (const float*)d_in[11];
  const float* ln2_b   = (const float*)d_in[12];
  const float* fc1_w   = (const float*)d_in[13];
  const float* fc1_b   = (const float*)d_in[14];
  const float* fc2_w   = (const float*)d_in[15];
  const float* fc2_b   = (const float*)d_in[16];
  const float* lnf_g   = (const float*)d_in[17];
  const float* lnf_b   = (const float*)d_in[18];
  const float* head_w  = (const float*)d_in[19];
  float* out = (float*)d_out;

  const size_t R = (size_t)BATCH * S_;  // 25216 token rows
  char* p = (char*)d_ws;
  float* h  = (float*)p; p += R * 384 * 4;       // fp32 residual
  bf16* u   = (bf16*)p;  p += R * 1536 * 2;      // union: qkvb|ctxb / hid / patches
  bf16* qkvb = u;                                 // R*1152
  bf16* ctxb = u + R * 1152;                      // R*384
  bf16* hidb = u;                                 // R*1536 (qkv/ctx dead by then)
  bf16* patches = u;                              // 25088*768 (pre-loop only)
  bf16* wb  = (bf16*)p;                           // bf16 weights
  bf16* patch_wb = wb;                            // 768*384
  bf16* qkv_wb   = patch_wb + 294912;             // 12*1152*384
  bf16* out_wb   = qkv_wb + 5308416;              // 12*384*384
  bf16* fc1_wb   = out_wb + 1769472;              // 12*1536*384
  bf16* fc2_wb   = fc1_wb + 7077888;              // 12*384*1536
  p = (char*)(fc2_wb + 7077888);
  float* qkv_bf = (float*)p; p += 12 * 1152 * 4;  // LN-beta-folded biases
  float* fc1_bf = (float*)p;

  // weight conversion fp32 -> bf16 (gamma folded for qkv/fc1); graph-safe
  k_f2b<<<dim3((294912 / 4 + 255) / 256), dim3(256), 0, stream>>>(patch_w, patch_wb, 294912 / 4);
  k_f2b_g<<<dim3((5308416 / 4 + 255) / 256), dim3(256), 0, stream>>>(qkv_w, ln1_g, qkv_wb, 5308416 / 4, 1152);
  k_f2b<<<dim3((1769472 / 4 + 255) / 256), dim3(256), 0, stream>>>(out_w, out_wb, 1769472 / 4);
  k_f2b_g<<<dim3((7077888 / 4 + 255) / 256), dim3(256), 0, stream>>>(fc1_w, ln2_g, fc1_wb, 7077888 / 4, 1536);
  k_f2b<<<dim3((7077888 / 4 + 255) / 256), dim3(256), 0, stream>>>(fc2_w, fc2_wb, 7077888 / 4);
  k_biasfold<<<dim3((12 * 1152 + 255) / 256), dim3(256), 0, stream>>>(qkv_w, ln1_b, qkv_b, qkv_bf, 1152);
  k_biasfold<<<dim3((12 * 1536 + 255) / 256), dim3(256), 0, stream>>>(fc1_w, ln2_b, fc1_b, fc1_bf, 1536);

  k_embed_init<<<dim3((BATCH * S_ * D_) / 256), dim3(256), 0, stream>>>(cls_tok, pos_emb, h);
  k_patchify<<<dim3((BATCH * 196 * 768) / 256), dim3(256), 0, stream>>>(x, patches);
  // tok = patches @ patch_w^T + patch_b, accumulated into h (row remap b*196+n -> b*197+1+n)
  k_gemm<2, 0><<<dim3(3, 196), dim3(256), 0, stream>>>(patches, patch_wb, patch_b, nullptr, h,
                                                       nullptr, 384, 768, 1);

  for (int i = 0; i < 12; i++) {
    // qkv = LN1(h) @ (g1.qkv_w)^T + (qkv_b + b1.qkv_w^T)   [LN fused]
    k_gemm<0, 1><<<dim3(9, 197), dim3(256), 0, stream>>>(nullptr, qkv_wb + (size_t)i * 1152 * 384,
                                                         qkv_bf + i * 1152, qkvb, nullptr, h,
                                                         1152, 384, 0);
    k_attn<<<dim3(768), dim3(256), 0, stream>>>(qkvb, ctxb);
    k_gemm<2, 0><<<dim3(3, 197), dim3(256), 0, stream>>>(ctxb, out_wb + (size_t)i * 384 * 384,
                                                         out_b + i * 384, nullptr, h, nullptr,
                                                         384, 384, 0);
    // hid = gelu(LN2(h) @ (g2.fc1_w)^T + (fc1_b + b2.fc1_w^T))   [LN fused]
    k_gemm<1, 1><<<dim3(12, 197), dim3(256), 0, stream>>>(nullptr, fc1_wb + (size_t)i * 1536 * 384,
                                                          fc1_bf + i * 1536, hidb, nullptr, h,
                                                          1536, 384, 0);
    k_gemm<2, 0><<<dim3(3, 197), dim3(256), 0, stream>>>(hidb, fc2_wb + (size_t)i * 384 * 1536,
                                                         fc2_b + i * 384, nullptr, h, nullptr,
                                                         384, 1536, 0);
  }
  k_head<<<dim3(128), dim3(128), 0, stream>>>(h, lnf_g, lnf_b, head_w, out);
}

// Round 5
// 3923.287 us; speedup vs baseline: 1.2930x; 1.2930x over previous
//
#include <hip/hip_runtime.h>
#include <hip/hip_bf16.h>

// ViT-S/16 forward, B=128. Inputs/outputs fp32 (per reference). Internal:
// weights+activations bf16 for MFMA, residual stream fp32, LN/softmax fp32.
// R5: k_gemm = double-buffered LDS (one barrier/iter) + XOR chunk-swizzle.
// R8/R9: LayerNorm fused into consuming GEMM (qkv, fc1); gamma folded into
// bf16 weights, beta into bias. Passed (absmax 0.0101) but regressed: the
// grid.x n-blocks of an m-row re-fetched the fp32 A-panel from HBM (FETCH
// 318 MB on qkv/fc1) because round-robin dispatch scatters them across XCDs
// whose L2s are not shared.
// R10: XCD-aware bijective block swizzle (T1 / m204 formula) in k_gemm:
// lid%8 picks the XCD chunk, so all n-tiles of an m-row run consecutively
// on ONE XCD -> A-panel fetched once into that L2, W stays L2-resident.
// Applies to all k_gemm launches; k_attn has no inter-block reuse.

#define S_ 197
#define D_ 384
#define BATCH 128

using bf16 = __hip_bfloat16;
typedef __attribute__((ext_vector_type(8))) __bf16 bf16x8;
typedef __attribute__((ext_vector_type(4))) float f32x4;

#if __has_builtin(__builtin_amdgcn_global_load_lds)
#define HAVE_GLL 1
__device__ __forceinline__ void gll16(const bf16* g, __bf16* l) {
  __builtin_amdgcn_global_load_lds(
      (const __attribute__((address_space(1))) void*)g,
      (__attribute__((address_space(3))) void*)l, 16, 0, 0);
}
#else
#define HAVE_GLL 0
#endif

// fp32 -> bf16 (RN), 4 elements/thread. n must be a multiple of 4.
__global__ __launch_bounds__(256) void k_f2b(const float* __restrict__ src,
                                             bf16* __restrict__ dst, int n4) {
  int i = blockIdx.x * 256 + threadIdx.x;
  if (i >= n4) return;
  float4 v = ((const float4*)src)[i];
  bf16 o[4] = {__float2bfloat16(v.x), __float2bfloat16(v.y),
               __float2bfloat16(v.z), __float2bfloat16(v.w)};
  ((uint2*)dst)[i] = *(uint2*)o;
}

// fp32 -> bf16 with columnwise LN-gamma fold: dst = bf16(src * g[layer][col]).
// W layout [12][rowsPerLayer][384]; col = elem % 384.
__global__ __launch_bounds__(256) void k_f2b_g(const float* __restrict__ src,
                                               const float* __restrict__ g,
                                               bf16* __restrict__ dst, int n4,
                                               int rowsPerLayer) {
  int i = blockIdx.x * 256 + threadIdx.x;
  if (i >= n4) return;
  size_t base = (size_t)i * 4;
  int col = (int)(base % 384);
  int layer = (int)(base / ((size_t)rowsPerLayer * 384));
  float4 v = ((const float4*)src)[i];
  float4 gg = *(const float4*)(g + (size_t)layer * 384 + col);
  bf16 o[4] = {__float2bfloat16(v.x * gg.x), __float2bfloat16(v.y * gg.y),
               __float2bfloat16(v.z * gg.z), __float2bfloat16(v.w * gg.w)};
  ((uint2*)dst)[i] = *(uint2*)o;
}

// LN-beta fold into bias: outb[l][n] = base[l][n] + sum_k lnb[l][k]*W[l][n][k]
__global__ __launch_bounds__(256) void k_biasfold(const float* __restrict__ W,
                                                  const float* __restrict__ lnb,
                                                  const float* __restrict__ base,
                                                  float* __restrict__ outb,
                                                  int rowsPerLayer) {
  int n = blockIdx.x * 256 + threadIdx.x;
  if (n >= 12 * rowsPerLayer) return;
  int layer = n / rowsPerLayer, r = n % rowsPerLayer;
  const float* wr = W + ((size_t)layer * rowsPerLayer + r) * 384;
  const float* bb = lnb + (size_t)layer * 384;
  float a = base[n];
  for (int k = 0; k < 384; k += 4) {
    float4 wv = *(const float4*)(wr + k);
    float4 bv = *(const float4*)(bb + k);
    a += wv.x * bv.x + wv.y * bv.y + wv.z * bv.z + wv.w * bv.w;
  }
  outb[n] = a;
}

__global__ __launch_bounds__(256) void k_embed_init(const float* __restrict__ cls,
                                                    const float* __restrict__ pos,
                                                    float* __restrict__ h) {
  int idx = blockIdx.x * 256 + threadIdx.x;
  if (idx >= BATCH * S_ * D_) return;
  int d = idx % D_;
  int s = (idx / D_) % S_;
  float v = pos[s * D_ + d];
  if (s == 0) v += cls[d];
  h[idx] = v;
}

__global__ __launch_bounds__(256) void k_patchify(const float* __restrict__ x,
                                                  bf16* __restrict__ patches) {
  int idx = blockIdx.x * 256 + threadIdx.x;
  if (idx >= BATCH * 196 * 768) return;
  int f = idx % 768;
  int n = (idx / 768) % 196;
  int b = idx / (768 * 196);
  int c = f >> 8, rem = f & 255, dy = rem >> 4, dx = rem & 15;
  int py = n / 14, px = n % 14;
  patches[idx] = __float2bfloat16(
      x[(((size_t)b * 3 + c) * 224 + py * 16 + dy) * 224 + px * 16 + dx]);
}

// out[M,N] = A[M,K] @ W[N,K]^T + bias.  Grid: (N/128, M/128), 256 threads.
// MODE 0: out=bf16(v); MODE 1: out=bf16(gelu_exact(v)); MODE 2: res(f32)+=v
// LNF 1: A-operand is LayerNorm'd fp32 residual Xf (gamma/beta pre-folded
//        into W/bias): per-block row stats prepass, normalize while staging.
// remap!=0 (patch embed): residual row = r + r/196 + 1
// XCD swizzle (R10): lid = by*gx+bx is assumed round-robin over 8 XCDs;
// bijective remap (m204): xcd's chunk = contiguous wgid range, wgid ordered
// n-fastest -> all n-tiles of an m-row on one XCD, back-to-back.
// LDS layout: row stride 32 elems (64B), 4 chunks of 8 elems per row; slot
// chunk j holds global chunk j ^ ((row>>1)&3)  -> b128 frag reads are 2-way
// bank-aliased (free). Double-buffered: prefetch k+1 while computing k.
template <int MODE, int LNF>
__global__ __launch_bounds__(256, 4) void k_gemm(
    const bf16* __restrict__ X, const bf16* __restrict__ W,
    const float* __restrict__ bias, bf16* __restrict__ out,
    float* __restrict__ res, const float* __restrict__ Xf,
    int N, int K, int remap) {
  __shared__ __align__(16) __bf16 As[2][128 * 32];
  __shared__ __align__(16) __bf16 Bs[2][128 * 32];
  __shared__ float smean[128], srstd[128];
  const int tid = threadIdx.x;

  // --- XCD-aware bijective swizzle (T1) ---
  const int gx = gridDim.x;
  const int nwg = gx * gridDim.y;
  const int lid = blockIdx.y * gx + blockIdx.x;
  const int xcd = lid & 7, sseq = lid >> 3;
  const int q8 = nwg >> 3, r8 = nwg & 7;
  const int start = xcd * q8 + (xcd < r8 ? xcd : r8);
  const int wgid = start + sseq;
  const int m0 = (wgid / gx) * 128, n0 = (wgid % gx) * 128;

  const int lane = tid & 63, w = tid >> 6;
  const int wr = w >> 1, wc = w & 1;
  const int l16 = lane & 15, quad = lane >> 4;
  f32x4 acc[4][4] = {};

  // staging: wave w covers tile rows w*32..w*32+31; lane -> slot row
  // (lane>>2), slot chunk (lane&3); global chunk swizzled:
  // c = (lane&3) ^ ((lane>>3)&3)
  const int srow = w * 32 + (lane >> 2);
  const int scol = (((lane & 3) ^ ((lane >> 3) & 3)) << 3);
  const bf16* Ag = LNF ? nullptr : X + (size_t)(m0 + srow) * K + scol;
  const bf16* Bg = W + (size_t)(n0 + srow) * K + scol;
  const int ldsW = w * 32 * 32;  // wave-uniform LDS base offset (elems)

  const float* hA = nullptr;
  float mA0 = 0.f, rA0 = 0.f, mA1 = 0.f, rA1 = 0.f;
  if constexpr (LNF) {
    // row-stats prepass: wave w handles rows w*32..w*32+31; 8 lanes/row,
    // 48 contiguous cols/lane (K==384).
    for (int rr = 0; rr < 4; rr++) {
      const int r = w * 32 + rr * 8 + (lane >> 3);
      const float* hr = Xf + (size_t)(m0 + r) * 384 + (lane & 7) * 48;
      float s = 0.f, q = 0.f;
#pragma unroll
      for (int c = 0; c < 12; c++) {
        float4 v = ((const float4*)hr)[c];
        s += v.x + v.y + v.z + v.w;
        q += v.x * v.x + v.y * v.y + v.z * v.z + v.w * v.w;
      }
#pragma unroll
      for (int o = 1; o < 8; o <<= 1) {
        s += __shfl_xor(s, o);
        q += __shfl_xor(q, o);
      }
      if ((lane & 7) == 0) {
        float m = s * (1.f / 384.f);
        smean[r] = m;
        srstd[r] = rsqrtf(q * (1.f / 384.f) - m * m + 1e-5f);
      }
    }
    __syncthreads();
    hA = Xf + (size_t)(m0 + srow) * 384 + scol;
    mA0 = smean[srow];      rA0 = srstd[srow];
    mA1 = smean[srow + 16]; rA1 = srstd[srow + 16];
  }

  // fragment read offsets: row r needs global chunk `quad`, stored at slot
  // chunk quad ^ ((l16>>1)&3)
  const int jx8 = ((quad ^ ((l16 >> 1) & 3)) << 3);
  const int aoff = (wr * 64 + l16) * 32 + jx8;
  const int boff = (wc * 64 + l16) * 32 + jx8;

  auto stageA_ln = [&](int buf, int k0) {
    float4 u0 = *(const float4*)(hA + k0);
    float4 u1 = *(const float4*)(hA + k0 + 4);
    float4 v0 = *(const float4*)(hA + 16 * 384 + k0);
    float4 v1 = *(const float4*)(hA + 16 * 384 + k0 + 4);
    bf16 t0[8] = {__float2bfloat16((u0.x - mA0) * rA0),
                  __float2bfloat16((u0.y - mA0) * rA0),
                  __float2bfloat16((u0.z - mA0) * rA0),
                  __float2bfloat16((u0.w - mA0) * rA0),
                  __float2bfloat16((u1.x - mA0) * rA0),
                  __float2bfloat16((u1.y - mA0) * rA0),
                  __float2bfloat16((u1.z - mA0) * rA0),
                  __float2bfloat16((u1.w - mA0) * rA0)};
    bf16 t1[8] = {__float2bfloat16((v0.x - mA1) * rA1),
                  __float2bfloat16((v0.y - mA1) * rA1),
                  __float2bfloat16((v0.z - mA1) * rA1),
                  __float2bfloat16((v0.w - mA1) * rA1),
                  __float2bfloat16((v1.x - mA1) * rA1),
                  __float2bfloat16((v1.y - mA1) * rA1),
                  __float2bfloat16((v1.z - mA1) * rA1),
                  __float2bfloat16((v1.w - mA1) * rA1)};
    *(uint4*)(&As[buf][ldsW + (lane >> 2) * 32 + (lane & 3) * 8]) = *(uint4*)t0;
    *(uint4*)(&As[buf][ldsW + 512 + (lane >> 2) * 32 + (lane & 3) * 8]) = *(uint4*)t1;
  };

#if HAVE_GLL
#define STAGE(buf, k0)                                           \
  do {                                                           \
    if constexpr (LNF) {                                         \
      stageA_ln(buf, k0);                                        \
    } else {                                                     \
      gll16(Ag + (k0), &As[buf][ldsW]);                          \
      gll16(Ag + (k0) + (size_t)16 * K, &As[buf][ldsW + 512]);   \
    }                                                            \
    gll16(Bg + (k0), &Bs[buf][ldsW]);                            \
    gll16(Bg + (k0) + (size_t)16 * K, &Bs[buf][ldsW + 512]);     \
  } while (0)
#else
#define STAGE(buf, k0)                                                        \
  do {                                                                        \
    if constexpr (LNF) {                                                      \
      stageA_ln(buf, k0);                                                     \
    } else {                                                                  \
      *(uint4*)(&As[buf][ldsW + (lane >> 2) * 32 + (lane & 3) * 8]) =         \
          *(const uint4*)(Ag + (k0));                                         \
      *(uint4*)(&As[buf][ldsW + 512 + (lane >> 2) * 32 + (lane & 3) * 8]) =   \
          *(const uint4*)(Ag + (k0) + (size_t)16 * K);                        \
    }                                                                         \
    *(uint4*)(&Bs[buf][ldsW + (lane >> 2) * 32 + (lane & 3) * 8]) =           \
        *(const uint4*)(Bg + (k0));                                           \
    *(uint4*)(&Bs[buf][ldsW + 512 + (lane >> 2) * 32 + (lane & 3) * 8]) =     \
        *(const uint4*)(Bg + (k0) + (size_t)16 * K);                          \
  } while (0)
#endif

  STAGE(0, 0);
  __syncthreads();
  for (int k0 = 0; k0 < K; k0 += 32) {
    const int cb = (k0 >> 5) & 1;
    if (k0 + 32 < K) STAGE(cb ^ 1, k0 + 32);
    bf16x8 av[4], bv[4];
#pragma unroll
    for (int i = 0; i < 4; i++)
      av[i] = *(const bf16x8*)(&As[cb][aoff + i * 512]);
#pragma unroll
    for (int j = 0; j < 4; j++)
      bv[j] = *(const bf16x8*)(&Bs[cb][boff + j * 512]);
#pragma unroll
    for (int i = 0; i < 4; i++)
#pragma unroll
      for (int j = 0; j < 4; j++)
        acc[i][j] = __builtin_amdgcn_mfma_f32_16x16x32_bf16(av[i], bv[j], acc[i][j], 0, 0, 0);
    __syncthreads();
  }
#undef STAGE

  float bvv[4];
#pragma unroll
  for (int j = 0; j < 4; j++)
    bvv[j] = bias[n0 + wc * 64 + j * 16 + l16];
#pragma unroll
  for (int i = 0; i < 4; i++) {
    const int rbase = m0 + wr * 64 + i * 16 + quad * 4;
#pragma unroll
    for (int j = 0; j < 4; j++) {
      const int col = n0 + wc * 64 + j * 16 + l16;
#pragma unroll
      for (int r = 0; r < 4; r++) {
        float v = acc[i][j][r] + bvv[j];
        int rw = rbase + r;
        if (MODE == 0) {
          out[(size_t)rw * N + col] = __float2bfloat16(v);
        } else if (MODE == 1) {
          float gl = 0.5f * v * (1.f + erff(v * 0.70710678118f));
          out[(size_t)rw * N + col] = __float2bfloat16(gl);
        } else {
          int hr = remap ? (rw + rw / 196 + 1) : rw;
          res[(size_t)hr * N + col] += v;
        }
      }
    }
  }
}

// MFMA flash attention. One block per (b, head), 4 waves. Each wave owns
// q-bands {w, w+4, w+8, ...} of 16 rows: QK^T (13 col-tiles, K=64) -> masked
// softmax (band-local, shuffle over l16 only) -> P band to LDS (C->A layout
// round-trip) -> P@V via LDS V^T. No __syncthreads after staging.
__global__ __launch_bounds__(256) void k_attn(const bf16* __restrict__ qkv,
                                              bf16* __restrict__ ctx) {
  const int bh = blockIdx.x;
  const int b = bh / 6, hd = bh % 6;
  const bf16* Qg = qkv + (size_t)b * S_ * 1152 + hd * 64;
  const bf16* Kg = Qg + 384;
  const bf16* Vg = Qg + 768;
  // Vt[d][k] = V[k][d]; stride 232 (116 dw -> 2-way bank alias = free)
  __shared__ __align__(16) __bf16 Vt[64 * 232];
  __shared__ __align__(16) __bf16 Ps[4][16 * 232];
  const int tid = threadIdx.x;
  const int lane = tid & 63, w = tid >> 6;
  const int l16 = lane & 15, quad = lane >> 4;
  const __bf16 z = (__bf16)0.0f;

  // zero Vt pad cols (k = 197..231)
  for (int i = tid; i < 64 * 35; i += 256) {
    int d = i / 35, k = 197 + i % 35;
    Vt[d * 232 + k] = z;
  }
  // stage V transposed
  for (int i = tid; i < S_ * 64; i += 256) {
    int k = i >> 6, d = i & 63;
    Vt[d * 232 + k] = *(const __bf16*)&Vg[(size_t)k * 1152 + d];
  }
  // zero own Ps pad cols (208..231)
  for (int i = lane; i < 16 * 24; i += 64) {
    int r = i / 24, c = 208 + i % 24;
    Ps[w][r * 232 + c] = z;
  }
  __syncthreads();

  const bf16x8 zf = {};
  for (int band = w; band < 13; band += 4) {
    // Q A-fragments (row = band*16 + l16), predicated on row < 197
    const int qrow = band * 16 + l16;
    bf16x8 aq0 = zf, aq1 = zf;
    if (qrow < S_) {
      aq0 = *(const bf16x8*)(Qg + (size_t)qrow * 1152 + quad * 8);
      aq1 = *(const bf16x8*)(Qg + (size_t)qrow * 1152 + 32 + quad * 8);
    }
    // scores: 13 col-tiles of 16
    f32x4 sc[13];
#pragma unroll
    for (int t = 0; t < 13; t++) {
      const int krow = t * 16 + l16;
      bf16x8 bk0 = zf, bk1 = zf;
      if (krow < S_) {
        bk0 = *(const bf16x8*)(Kg + (size_t)krow * 1152 + quad * 8);
        bk1 = *(const bf16x8*)(Kg + (size_t)krow * 1152 + 32 + quad * 8);
      }
      f32x4 a = {};
      a = __builtin_amdgcn_mfma_f32_16x16x32_bf16(aq0, bk0, a, 0, 0, 0);
      a = __builtin_amdgcn_mfma_f32_16x16x32_bf16(aq1, bk1, a, 0, 0, 0);
      sc[t] = a;
    }
    // scale 1/sqrt(64), mask pad cols (192+l16 >= 197)
#pragma unroll
    for (int t = 0; t < 13; t++)
#pragma unroll
      for (int r = 0; r < 4; r++) sc[t][r] *= 0.125f;
    if (l16 >= 5) {
#pragma unroll
      for (int r = 0; r < 4; r++) sc[12][r] = -1e30f;
    }
    // row max (across 13 tiles in-reg, then across the 16 lanes of this quad)
    f32x4 mx = sc[0];
#pragma unroll
    for (int t = 1; t < 13; t++)
#pragma unroll
      for (int r = 0; r < 4; r++) mx[r] = fmaxf(mx[r], sc[t][r]);
#pragma unroll
    for (int o = 1; o < 16; o <<= 1)
#pragma unroll
      for (int r = 0; r < 4; r++) mx[r] = fmaxf(mx[r], __shfl_xor(mx[r], o));
    // exp + row sum
    f32x4 sum = {};
#pragma unroll
    for (int t = 0; t < 13; t++)
#pragma unroll
      for (int r = 0; r < 4; r++) {
        float p = __expf(sc[t][r] - mx[r]);
        sc[t][r] = p;
        sum[r] += p;
      }
#pragma unroll
    for (int o = 1; o < 16; o <<= 1)
#pragma unroll
      for (int r = 0; r < 4; r++) sum[r] += __shfl_xor(sum[r], o);
    f32x4 rinv;
#pragma unroll
    for (int r = 0; r < 4; r++) rinv[r] = 1.0f / sum[r];
    // write unnormalized P band (C layout -> LDS); pad cols 197..207 are
    // exact zeros (exp(-1e30-m) underflows to 0)
#pragma unroll
    for (int t = 0; t < 13; t++)
#pragma unroll
      for (int r = 0; r < 4; r++)
        Ps[w][(quad * 4 + r) * 232 + t * 16 + l16] = (__bf16)sc[t][r];
    // P @ V: out cols d = c*16 + l16, k over 224 (7 steps of 32)
    f32x4 oacc[4] = {};
#pragma unroll
    for (int ks = 0; ks < 7; ks++) {
      bf16x8 pa = *(const bf16x8*)&Ps[w][l16 * 232 + ks * 32 + quad * 8];
#pragma unroll
      for (int c = 0; c < 4; c++) {
        bf16x8 bv = *(const bf16x8*)&Vt[(c * 16 + l16) * 232 + ks * 32 + quad * 8];
        oacc[c] = __builtin_amdgcn_mfma_f32_16x16x32_bf16(pa, bv, oacc[c], 0, 0, 0);
      }
    }
    // epilogue: rows band*16 + quad*4 + r (guarded), cols hd*64 + c*16 + l16
    const int orow = band * 16 + quad * 4;
#pragma unroll
    for (int c = 0; c < 4; c++)
#pragma unroll
      for (int r = 0; r < 4; r++) {
        const int rw = orow + r;
        if (rw < S_)
          ctx[((size_t)b * S_ + rw) * D_ + hd * 64 + c * 16 + l16] =
              __float2bfloat16(oacc[c][r] * rinv[r]);
      }
  }
}

__global__ __launch_bounds__(128) void k_head(const float* __restrict__ h,
                                              const float* __restrict__ g,
                                              const float* __restrict__ bt,
                                              const float* __restrict__ hw,
                                              float* __restrict__ out) {
  const int b = blockIdx.x, t = threadIdx.x;
  const float* row = h + (size_t)b * S_ * D_;
  float x0 = row[t], x1 = row[t + 128], x2 = row[t + 256];
  float s = x0 + x1 + x2;
  float q = x0 * x0 + x1 * x1 + x2 * x2;
#pragma unroll
  for (int o = 32; o; o >>= 1) {
    s += __shfl_xor(s, o);
    q += __shfl_xor(q, o);
  }
  __shared__ float rs[2], rq[2];
  if ((t & 63) == 0) { rs[t >> 6] = s; rq[t >> 6] = q; }
  __syncthreads();
  s = rs[0] + rs[1];
  q = rq[0] + rq[1];
  const float mean = s * (1.f / 384.f);
  const float var = q * (1.f / 384.f) - mean * mean;
  const float rstd = rsqrtf(var + 1e-5f);
  __shared__ float clsn[384];
  clsn[t] = (x0 - mean) * rstd * g[t] + bt[t];
  clsn[t + 128] = (x1 - mean) * rstd * g[t + 128] + bt[t + 128];
  clsn[t + 256] = (x2 - mean) * rstd * g[t + 256] + bt[t + 256];
  __syncthreads();
  if (t < 100) {
    const float* wr = hw + (size_t)t * D_;
    float a = 0.f;
    for (int d = 0; d < 384; d++) a += clsn[d] * wr[d];
    out[b * 100 + t] = a;
  }
}

extern "C" void kernel_launch(void* const* d_in, const int* in_sizes, int n_in,
                              void* d_out, int out_size, void* d_ws, size_t ws_size,
                              hipStream_t stream) {
  (void)in_sizes; (void)n_in; (void)out_size; (void)ws_size;
  const float* x       = (const float*)d_in[0];
  const float* patch_w = (const float*)d_in[1];
  const float* patch_b = (const float*)d_in[2];
  const float* cls_tok = (const float*)d_in[3];
  const float* pos_emb = (const float*)d_in[4];
  const float* ln1_g   = (const float*)d_in[5];
  const float* ln1_b   = (const float*)d_in[6];
  const float* qkv_w   = (const float*)d_in[7];
  const float* qkv_b   = (const float*)d_in[8];
  const float* out_w   = (const float*)d_in[9];
  const float* out_b   = (const float*)d_in[10];
  const float* ln2_g   = (const float*)d_in[11];
  const float* ln2_b   = (const float*)d_in[12];
  const float* fc1_w   = (const float*)d_in[13];
  const float* fc1_b   = (const float*)d_in[14];
  const float* fc2_w   = (const float*)d_in[15];
  const float* fc2_b   = (const float*)d_in[16];
  const float* lnf_g   = (const float*)d_in[17];
  const float* lnf_b   = (const float*)d_in[18];
  const float* head_w  = (const float*)d_in[19];
  float* out = (float*)d_out;

  const size_t R = (size_t)BATCH * S_;  // 25216 token rows
  char* p = (char*)d_ws;
  float* h  = (float*)p; p += R * 384 * 4;       // fp32 residual
  bf16* u   = (bf16*)p;  p += R * 1536 * 2;      // union: qkvb|ctxb / hid / patches
  bf16* qkvb = u;                                 // R*1152
  bf16* ctxb = u + R * 1152;                      // R*384
  bf16* hidb = u;                                 // R*1536 (qkv/ctx dead by then)
  bf16* patches = u;                              // 25088*768 (pre-loop only)
  bf16* wb  = (bf16*)p;                           // bf16 weights
  bf16* patch_wb = wb;                            // 768*384
  bf16* qkv_wb   = patch_wb + 294912;             // 12*1152*384
  bf16* out_wb   = qkv_wb + 5308416;              // 12*384*384
  bf16* fc1_wb   = out_wb + 1769472;              // 12*1536*384
  bf16* fc2_wb   = fc1_wb + 7077888;              // 12*384*1536
  p = (char*)(fc2_wb + 7077888);
  float* qkv_bf = (float*)p; p += 12 * 1152 * 4;  // LN-beta-folded biases
  float* fc1_bf = (float*)p;

  // weight conversion fp32 -> bf16 (gamma folded for qkv/fc1); graph-safe
  k_f2b<<<dim3((294912 / 4 + 255) / 256), dim3(256), 0, stream>>>(patch_w, patch_wb, 294912 / 4);
  k_f2b_g<<<dim3((5308416 / 4 + 255) / 256), dim3(256), 0, stream>>>(qkv_w, ln1_g, qkv_wb, 5308416 / 4, 1152);
  k_f2b<<<dim3((1769472 / 4 + 255) / 256), dim3(256), 0, stream>>>(out_w, out_wb, 1769472 / 4);
  k_f2b_g<<<dim3((7077888 / 4 + 255) / 256), dim3(256), 0, stream>>>(fc1_w, ln2_g, fc1_wb, 7077888 / 4, 1536);
  k_f2b<<<dim3((7077888 / 4 + 255) / 256), dim3(256), 0, stream>>>(fc2_w, fc2_wb, 7077888 / 4);
  k_biasfold<<<dim3((12 * 1152 + 255) / 256), dim3(256), 0, stream>>>(qkv_w, ln1_b, qkv_b, qkv_bf, 1152);
  k_biasfold<<<dim3((12 * 1536 + 255) / 256), dim3(256), 0, stream>>>(fc1_w, ln2_b, fc1_b, fc1_bf, 1536);

  k_embed_init<<<dim3((BATCH * S_ * D_) / 256), dim3(256), 0, stream>>>(cls_tok, pos_emb, h);
  k_patchify<<<dim3((BATCH * 196 * 768) / 256), dim3(256), 0, stream>>>(x, patches);
  // tok = patches @ patch_w^T + patch_b, accumulated into h (row remap b*196+n -> b*197+1+n)
  k_gemm<2, 0><<<dim3(3, 196), dim3(256), 0, stream>>>(patches, patch_wb, patch_b, nullptr, h,
                                                       nullptr, 384, 768, 1);

  for (int i = 0; i < 12; i++) {
    // qkv = LN1(h) @ (g1.qkv_w)^T + (qkv_b + b1.qkv_w^T)   [LN fused]
    k_gemm<0, 1><<<dim3(9, 197), dim3(256), 0, stream>>>(nullptr, qkv_wb + (size_t)i * 1152 * 384,
                                                         qkv_bf + i * 1152, qkvb, nullptr, h,
                                                         1152, 384, 0);
    k_attn<<<dim3(768), dim3(256), 0, stream>>>(qkvb, ctxb);
    k_gemm<2, 0><<<dim3(3, 197), dim3(256), 0, stream>>>(ctxb, out_wb + (size_t)i * 384 * 384,
                                                         out_b + i * 384, nullptr, h, nullptr,
                                                         384, 384, 0);
    // hid = gelu(LN2(h) @ (g2.fc1_w)^T + (fc1_b + b2.fc1_w^T))   [LN fused]
    k_gemm<1, 1><<<dim3(12, 197), dim3(256), 0, stream>>>(nullptr, fc1_wb + (size_t)i * 1536 * 384,
                                                          fc1_bf + i * 1536, hidb, nullptr, h,
                                                          1536, 384, 0);
    k_gemm<2, 0><<<dim3(3, 197), dim3(256), 0, stream>>>(hidb, fc2_wb + (size_t)i * 384 * 1536,
                                                         fc2_b + i * 384, nullptr, h, nullptr,
                                                         384, 1536, 0);
  }
  k_head<<<dim3(128), dim3(128), 0, stream>>>(h, lnf_g, lnf_b, head_w, out);
}

// Round 6
// 3463.288 us; speedup vs baseline: 1.4648x; 1.1328x over previous
//
#include <hip/hip_runtime.h>
#include <hip/hip_bf16.h>

// ViT-S/16 forward, B=128. Inputs/outputs fp32 (per reference). Internal:
// weights+activations bf16 for MFMA, residual stream fp32, LN/softmax fp32.
// R5: k_gemm = double-buffered LDS (one barrier/iter) + XOR chunk-swizzle.
// R8-R10 post-mortem: LN-fusion into the GEMM cut LN traffic but made the
// staging path VALU-bound (each of 9-12 n-blocks re-normalized the same
// A-panel: VALUBusy 48%, 1.1 TB/s). The XCD swizzle, however, collapsed
// A re-fetch 318->34 MB. R11: keep the XCD-aware bijective block swizzle
// (T1/m204), revert LN to the separate k_ln + bf16 xn dataflow so all GEMM
// staging is global_load_lds again. Swizzle should now also fix fc2's
// 137->~80 MB A re-fetch from R5.

#define S_ 197
#define D_ 384
#define BATCH 128

using bf16 = __hip_bfloat16;
typedef __attribute__((ext_vector_type(8))) __bf16 bf16x8;
typedef __attribute__((ext_vector_type(4))) float f32x4;

#if __has_builtin(__builtin_amdgcn_global_load_lds)
#define HAVE_GLL 1
__device__ __forceinline__ void gll16(const bf16* g, __bf16* l) {
  __builtin_amdgcn_global_load_lds(
      (const __attribute__((address_space(1))) void*)g,
      (__attribute__((address_space(3))) void*)l, 16, 0, 0);
}
#else
#define HAVE_GLL 0
#endif

// fp32 -> bf16 (RN), 4 elements/thread. n must be a multiple of 4.
__global__ __launch_bounds__(256) void k_f2b(const float* __restrict__ src,
                                             bf16* __restrict__ dst, int n4) {
  int i = blockIdx.x * 256 + threadIdx.x;
  if (i >= n4) return;
  float4 v = ((const float4*)src)[i];
  bf16 o[4] = {__float2bfloat16(v.x), __float2bfloat16(v.y),
               __float2bfloat16(v.z), __float2bfloat16(v.w)};
  ((uint2*)dst)[i] = *(uint2*)o;
}

__global__ __launch_bounds__(256) void k_embed_init(const float* __restrict__ cls,
                                                    const float* __restrict__ pos,
                                                    float* __restrict__ h) {
  int idx = blockIdx.x * 256 + threadIdx.x;
  if (idx >= BATCH * S_ * D_) return;
  int d = idx % D_;
  int s = (idx / D_) % S_;
  float v = pos[s * D_ + d];
  if (s == 0) v += cls[d];
  h[idx] = v;
}

__global__ __launch_bounds__(256) void k_patchify(const float* __restrict__ x,
                                                  bf16* __restrict__ patches) {
  int idx = blockIdx.x * 256 + threadIdx.x;
  if (idx >= BATCH * 196 * 768) return;
  int f = idx % 768;
  int n = (idx / 768) % 196;
  int b = idx / (768 * 196);
  int c = f >> 8, rem = f & 255, dy = rem >> 4, dx = rem & 15;
  int py = n / 14, px = n % 14;
  patches[idx] = __float2bfloat16(
      x[(((size_t)b * 3 + c) * 224 + py * 16 + dy) * 224 + px * 16 + dx]);
}

// out[M,N] = X[M,K] @ W[N,K]^T + bias.  Grid: (N/128, M/128), 256 threads.
// MODE 0: out=bf16(v); MODE 1: out=bf16(gelu_exact(v)); MODE 2: res(f32)+=v
// remap!=0 (patch embed): residual row = r + r/196 + 1  (b*196+n -> b*197+1+n)
// XCD swizzle (R10/R11): lid assumed round-robin over 8 XCDs; bijective
// remap (m204) gives each XCD a contiguous wgid chunk, wgid ordered
// n-fastest -> all n-tiles of an m-row on one XCD back-to-back, so the
// A-panel is fetched from HBM once and re-served from that XCD's L2.
// LDS layout: row stride 32 elems (64B), 4 chunks of 8 elems per row; slot
// chunk j holds global chunk j ^ ((row>>1)&3)  -> b128 frag reads are 2-way
// bank-aliased (free). Double-buffered: prefetch k+1 while computing k.
template <int MODE>
__global__ __launch_bounds__(256, 4) void k_gemm(const bf16* __restrict__ X,
                                                 const bf16* __restrict__ W,
                                                 const float* __restrict__ bias,
                                                 bf16* __restrict__ out,
                                                 float* __restrict__ res,
                                                 int N, int K, int remap) {
  __shared__ __align__(16) __bf16 As[2][128 * 32];
  __shared__ __align__(16) __bf16 Bs[2][128 * 32];
  const int tid = threadIdx.x;

  // --- XCD-aware bijective swizzle (T1/m204) ---
  const int gx = gridDim.x;
  const int nwg = gx * gridDim.y;
  const int lid = blockIdx.y * gx + blockIdx.x;
  const int xcd = lid & 7, sseq = lid >> 3;
  const int q8 = nwg >> 3, r8 = nwg & 7;
  const int start = xcd * q8 + (xcd < r8 ? xcd : r8);
  const int wgid = start + sseq;
  const int m0 = (wgid / gx) * 128, n0 = (wgid % gx) * 128;

  const int lane = tid & 63, w = tid >> 6;
  const int wr = w >> 1, wc = w & 1;
  const int l16 = lane & 15, quad = lane >> 4;
  f32x4 acc[4][4] = {};

  // staging: wave w covers tile rows w*32..w*32+31; 2 gll16 per matrix.
  // lane -> slot row (lane>>2), slot chunk (lane&3); global chunk swizzled:
  // c = (lane&3) ^ ((lane>>3)&3)
  const int srow = w * 32 + (lane >> 2);
  const int scol = (((lane & 3) ^ ((lane >> 3) & 3)) << 3);
  const bf16* Ag = X + (size_t)(m0 + srow) * K + scol;
  const bf16* Bg = W + (size_t)(n0 + srow) * K + scol;
  const int ldsW = w * 32 * 32;  // wave-uniform LDS base offset (elems)

  // fragment read offsets: row r needs global chunk `quad`, stored at slot
  // chunk quad ^ ((l16>>1)&3)
  const int jx8 = ((quad ^ ((l16 >> 1) & 3)) << 3);
  const int aoff = (wr * 64 + l16) * 32 + jx8;
  const int boff = (wc * 64 + l16) * 32 + jx8;

#if HAVE_GLL
#define STAGE(buf, k0)                                         \
  do {                                                         \
    gll16(Ag + (k0), &As[buf][ldsW]);                          \
    gll16(Ag + (k0) + (size_t)16 * K, &As[buf][ldsW + 512]);   \
    gll16(Bg + (k0), &Bs[buf][ldsW]);                          \
    gll16(Bg + (k0) + (size_t)16 * K, &Bs[buf][ldsW + 512]);   \
  } while (0)
#else
#define STAGE(buf, k0)                                                        \
  do {                                                                        \
    *(uint4*)(&As[buf][ldsW + (lane >> 2) * 32 + (lane & 3) * 8]) =           \
        *(const uint4*)(Ag + (k0));                                           \
    *(uint4*)(&As[buf][ldsW + 512 + (lane >> 2) * 32 + (lane & 3) * 8]) =     \
        *(const uint4*)(Ag + (k0) + (size_t)16 * K);                          \
    *(uint4*)(&Bs[buf][ldsW + (lane >> 2) * 32 + (lane & 3) * 8]) =           \
        *(const uint4*)(Bg + (k0));                                           \
    *(uint4*)(&Bs[buf][ldsW + 512 + (lane >> 2) * 32 + (lane & 3) * 8]) =     \
        *(const uint4*)(Bg + (k0) + (size_t)16 * K);                          \
  } while (0)
#endif

  STAGE(0, 0);
  __syncthreads();
  for (int k0 = 0; k0 < K; k0 += 32) {
    const int cb = (k0 >> 5) & 1;
    if (k0 + 32 < K) STAGE(cb ^ 1, k0 + 32);
    bf16x8 av[4], bv[4];
#pragma unroll
    for (int i = 0; i < 4; i++)
      av[i] = *(const bf16x8*)(&As[cb][aoff + i * 512]);
#pragma unroll
    for (int j = 0; j < 4; j++)
      bv[j] = *(const bf16x8*)(&Bs[cb][boff + j * 512]);
#pragma unroll
    for (int i = 0; i < 4; i++)
#pragma unroll
      for (int j = 0; j < 4; j++)
        acc[i][j] = __builtin_amdgcn_mfma_f32_16x16x32_bf16(av[i], bv[j], acc[i][j], 0, 0, 0);
    __syncthreads();
  }
#undef STAGE

  float bvv[4];
#pragma unroll
  for (int j = 0; j < 4; j++)
    bvv[j] = bias[n0 + wc * 64 + j * 16 + l16];
#pragma unroll
  for (int i = 0; i < 4; i++) {
    const int rbase = m0 + wr * 64 + i * 16 + quad * 4;
#pragma unroll
    for (int j = 0; j < 4; j++) {
      const int col = n0 + wc * 64 + j * 16 + l16;
#pragma unroll
      for (int r = 0; r < 4; r++) {
        float v = acc[i][j][r] + bvv[j];
        int rw = rbase + r;
        if (MODE == 0) {
          out[(size_t)rw * N + col] = __float2bfloat16(v);
        } else if (MODE == 1) {
          float gl = 0.5f * v * (1.f + erff(v * 0.70710678118f));
          out[(size_t)rw * N + col] = __float2bfloat16(gl);
        } else {
          int hr = remap ? (rw + rw / 196 + 1) : rw;
          res[(size_t)hr * N + col] += v;
        }
      }
    }
  }
}

__global__ __launch_bounds__(128) void k_ln(const float* __restrict__ h,
                                            const float* __restrict__ g,
                                            const float* __restrict__ bt,
                                            bf16* __restrict__ xn) {
  const int r = blockIdx.x, t = threadIdx.x;
  const float* row = h + (size_t)r * D_;
  float x0 = row[t], x1 = row[t + 128], x2 = row[t + 256];
  float s = x0 + x1 + x2;
  float q = x0 * x0 + x1 * x1 + x2 * x2;
#pragma unroll
  for (int o = 32; o; o >>= 1) {
    s += __shfl_xor(s, o);
    q += __shfl_xor(q, o);
  }
  __shared__ float rs[2], rq[2];
  if ((t & 63) == 0) { rs[t >> 6] = s; rq[t >> 6] = q; }
  __syncthreads();
  s = rs[0] + rs[1];
  q = rq[0] + rq[1];
  const float mean = s * (1.f / 384.f);
  const float var = q * (1.f / 384.f) - mean * mean;
  const float rstd = rsqrtf(var + 1e-5f);
  bf16* o = xn + (size_t)r * D_;
  o[t] = __float2bfloat16((x0 - mean) * rstd * g[t] + bt[t]);
  o[t + 128] = __float2bfloat16((x1 - mean) * rstd * g[t + 128] + bt[t + 128]);
  o[t + 256] = __float2bfloat16((x2 - mean) * rstd * g[t + 256] + bt[t + 256]);
}

// MFMA flash attention. One block per (b, head), 4 waves. Each wave owns
// q-bands {w, w+4, w+8, ...} of 16 rows: QK^T (13 col-tiles, K=64) -> masked
// softmax (band-local, shuffle over l16 only) -> P band to LDS (C->A layout
// round-trip) -> P@V via LDS V^T. No __syncthreads after staging.
__global__ __launch_bounds__(256) void k_attn(const bf16* __restrict__ qkv,
                                              bf16* __restrict__ ctx) {
  const int bh = blockIdx.x;
  const int b = bh / 6, hd = bh % 6;
  const bf16* Qg = qkv + (size_t)b * S_ * 1152 + hd * 64;
  const bf16* Kg = Qg + 384;
  const bf16* Vg = Qg + 768;
  // Vt[d][k] = V[k][d]; stride 232 (116 dw -> 2-way bank alias = free)
  __shared__ __align__(16) __bf16 Vt[64 * 232];
  __shared__ __align__(16) __bf16 Ps[4][16 * 232];
  const int tid = threadIdx.x;
  const int lane = tid & 63, w = tid >> 6;
  const int l16 = lane & 15, quad = lane >> 4;
  const __bf16 z = (__bf16)0.0f;

  // zero Vt pad cols (k = 197..231)
  for (int i = tid; i < 64 * 35; i += 256) {
    int d = i / 35, k = 197 + i % 35;
    Vt[d * 232 + k] = z;
  }
  // stage V transposed
  for (int i = tid; i < S_ * 64; i += 256) {
    int k = i >> 6, d = i & 63;
    Vt[d * 232 + k] = *(const __bf16*)&Vg[(size_t)k * 1152 + d];
  }
  // zero own Ps pad cols (208..231)
  for (int i = lane; i < 16 * 24; i += 64) {
    int r = i / 24, c = 208 + i % 24;
    Ps[w][r * 232 + c] = z;
  }
  __syncthreads();

  const bf16x8 zf = {};
  for (int band = w; band < 13; band += 4) {
    // Q A-fragments (row = band*16 + l16), predicated on row < 197
    const int qrow = band * 16 + l16;
    bf16x8 aq0 = zf, aq1 = zf;
    if (qrow < S_) {
      aq0 = *(const bf16x8*)(Qg + (size_t)qrow * 1152 + quad * 8);
      aq1 = *(const bf16x8*)(Qg + (size_t)qrow * 1152 + 32 + quad * 8);
    }
    // scores: 13 col-tiles of 16
    f32x4 sc[13];
#pragma unroll
    for (int t = 0; t < 13; t++) {
      const int krow = t * 16 + l16;
      bf16x8 bk0 = zf, bk1 = zf;
      if (krow < S_) {
        bk0 = *(const bf16x8*)(Kg + (size_t)krow * 1152 + quad * 8);
        bk1 = *(const bf16x8*)(Kg + (size_t)krow * 1152 + 32 + quad * 8);
      }
      f32x4 a = {};
      a = __builtin_amdgcn_mfma_f32_16x16x32_bf16(aq0, bk0, a, 0, 0, 0);
      a = __builtin_amdgcn_mfma_f32_16x16x32_bf16(aq1, bk1, a, 0, 0, 0);
      sc[t] = a;
    }
    // scale 1/sqrt(64), mask pad cols (192+l16 >= 197)
#pragma unroll
    for (int t = 0; t < 13; t++)
#pragma unroll
      for (int r = 0; r < 4; r++) sc[t][r] *= 0.125f;
    if (l16 >= 5) {
#pragma unroll
      for (int r = 0; r < 4; r++) sc[12][r] = -1e30f;
    }
    // row max (across 13 tiles in-reg, then across the 16 lanes of this quad)
    f32x4 mx = sc[0];
#pragma unroll
    for (int t = 1; t < 13; t++)
#pragma unroll
      for (int r = 0; r < 4; r++) mx[r] = fmaxf(mx[r], sc[t][r]);
#pragma unroll
    for (int o = 1; o < 16; o <<= 1)
#pragma unroll
      for (int r = 0; r < 4; r++) mx[r] = fmaxf(mx[r], __shfl_xor(mx[r], o));
    // exp + row sum
    f32x4 sum = {};
#pragma unroll
    for (int t = 0; t < 13; t++)
#pragma unroll
      for (int r = 0; r < 4; r++) {
        float p = __expf(sc[t][r] - mx[r]);
        sc[t][r] = p;
        sum[r] += p;
      }
#pragma unroll
    for (int o = 1; o < 16; o <<= 1)
#pragma unroll
      for (int r = 0; r < 4; r++) sum[r] += __shfl_xor(sum[r], o);
    f32x4 rinv;
#pragma unroll
    for (int r = 0; r < 4; r++) rinv[r] = 1.0f / sum[r];
    // write unnormalized P band (C layout -> LDS); pad cols 197..207 are
    // exact zeros (exp(-1e30-m) underflows to 0)
#pragma unroll
    for (int t = 0; t < 13; t++)
#pragma unroll
      for (int r = 0; r < 4; r++)
        Ps[w][(quad * 4 + r) * 232 + t * 16 + l16] = (__bf16)sc[t][r];
    // P @ V: out cols d = c*16 + l16, k over 224 (7 steps of 32)
    f32x4 oacc[4] = {};
#pragma unroll
    for (int ks = 0; ks < 7; ks++) {
      bf16x8 pa = *(const bf16x8*)&Ps[w][l16 * 232 + ks * 32 + quad * 8];
#pragma unroll
      for (int c = 0; c < 4; c++) {
        bf16x8 bv = *(const bf16x8*)&Vt[(c * 16 + l16) * 232 + ks * 32 + quad * 8];
        oacc[c] = __builtin_amdgcn_mfma_f32_16x16x32_bf16(pa, bv, oacc[c], 0, 0, 0);
      }
    }
    // epilogue: rows band*16 + quad*4 + r (guarded), cols hd*64 + c*16 + l16
    const int orow = band * 16 + quad * 4;
#pragma unroll
    for (int c = 0; c < 4; c++)
#pragma unroll
      for (int r = 0; r < 4; r++) {
        const int rw = orow + r;
        if (rw < S_)
          ctx[((size_t)b * S_ + rw) * D_ + hd * 64 + c * 16 + l16] =
              __float2bfloat16(oacc[c][r] * rinv[r]);
      }
  }
}

__global__ __launch_bounds__(128) void k_head(const float* __restrict__ h,
                                              const float* __restrict__ g,
                                              const float* __restrict__ bt,
                                              const float* __restrict__ hw,
                                              float* __restrict__ out) {
  const int b = blockIdx.x, t = threadIdx.x;
  const float* row = h + (size_t)b * S_ * D_;
  float x0 = row[t], x1 = row[t + 128], x2 = row[t + 256];
  float s = x0 + x1 + x2;
  float q = x0 * x0 + x1 * x1 + x2 * x2;
#pragma unroll
  for (int o = 32; o; o >>= 1) {
    s += __shfl_xor(s, o);
    q += __shfl_xor(q, o);
  }
  __shared__ float rs[2], rq[2];
  if ((t & 63) == 0) { rs[t >> 6] = s; rq[t >> 6] = q; }
  __syncthreads();
  s = rs[0] + rs[1];
  q = rq[0] + rq[1];
  const float mean = s * (1.f / 384.f);
  const float var = q * (1.f / 384.f) - mean * mean;
  const float rstd = rsqrtf(var + 1e-5f);
  __shared__ float clsn[384];
  clsn[t] = (x0 - mean) * rstd * g[t] + bt[t];
  clsn[t + 128] = (x1 - mean) * rstd * g[t + 128] + bt[t + 128];
  clsn[t + 256] = (x2 - mean) * rstd * g[t + 256] + bt[t + 256];
  __syncthreads();
  if (t < 100) {
    const float* wr = hw + (size_t)t * D_;
    float a = 0.f;
    for (int d = 0; d < 384; d++) a += clsn[d] * wr[d];
    out[b * 100 + t] = a;
  }
}

extern "C" void kernel_launch(void* const* d_in, const int* in_sizes, int n_in,
                              void* d_out, int out_size, void* d_ws, size_t ws_size,
                              hipStream_t stream) {
  (void)in_sizes; (void)n_in; (void)out_size; (void)ws_size;
  const float* x       = (const float*)d_in[0];
  const float* patch_w = (const float*)d_in[1];
  const float* patch_b = (const float*)d_in[2];
  const float* cls_tok = (const float*)d_in[3];
  const float* pos_emb = (const float*)d_in[4];
  const float* ln1_g   = (const float*)d_in[5];
  const float* ln1_b   = (const float*)d_in[6];
  const float* qkv_w   = (const float*)d_in[7];
  const float* qkv_b   = (const float*)d_in[8];
  const float* out_w   = (const float*)d_in[9];
  const float* out_b   = (const float*)d_in[10];
  const float* ln2_g   = (const float*)d_in[11];
  const float* ln2_b   = (const float*)d_in[12];
  const float* fc1_w   = (const float*)d_in[13];
  const float* fc1_b   = (const float*)d_in[14];
  const float* fc2_w   = (const float*)d_in[15];
  const float* fc2_b   = (const float*)d_in[16];
  const float* lnf_g   = (const float*)d_in[17];
  const float* lnf_b   = (const float*)d_in[18];
  const float* head_w  = (const float*)d_in[19];
  float* out = (float*)d_out;

  const size_t R = (size_t)BATCH * S_;  // 25216 token rows
  char* p = (char*)d_ws;
  float* h  = (float*)p; p += R * 384 * 4;       // fp32 residual
  bf16* xn  = (bf16*)p;  p += R * 384 * 2;       // LN output
  bf16* u   = (bf16*)p;  p += R * 1536 * 2;      // union: qkvb|ctxb / hid / patches
  bf16* qkvb = u;                                 // R*1152
  bf16* ctxb = u + R * 1152;                      // R*384
  bf16* hidb = u;                                 // R*1536 (qkv/ctx dead by then)
  bf16* patches = u;                              // 25088*768 (pre-loop only)
  bf16* wb  = (bf16*)p;                           // bf16 weights
  bf16* patch_wb = wb;                            // 768*384
  bf16* qkv_wb   = patch_wb + 294912;             // 12*1152*384
  bf16* out_wb   = qkv_wb + 5308416;              // 12*384*384
  bf16* fc1_wb   = out_wb + 1769472;              // 12*1536*384
  bf16* fc2_wb   = fc1_wb + 7077888;              // 12*384*1536

  // weight conversion fp32 -> bf16 (same work every launch; graph-safe)
  k_f2b<<<dim3((294912 / 4 + 255) / 256), dim3(256), 0, stream>>>(patch_w, patch_wb, 294912 / 4);
  k_f2b<<<dim3((5308416 / 4 + 255) / 256), dim3(256), 0, stream>>>(qkv_w, qkv_wb, 5308416 / 4);
  k_f2b<<<dim3((1769472 / 4 + 255) / 256), dim3(256), 0, stream>>>(out_w, out_wb, 1769472 / 4);
  k_f2b<<<dim3((7077888 / 4 + 255) / 256), dim3(256), 0, stream>>>(fc1_w, fc1_wb, 7077888 / 4);
  k_f2b<<<dim3((7077888 / 4 + 255) / 256), dim3(256), 0, stream>>>(fc2_w, fc2_wb, 7077888 / 4);

  k_embed_init<<<dim3((BATCH * S_ * D_) / 256), dim3(256), 0, stream>>>(cls_tok, pos_emb, h);
  k_patchify<<<dim3((BATCH * 196 * 768) / 256), dim3(256), 0, stream>>>(x, patches);
  // tok = patches @ patch_w^T + patch_b, accumulated into h (row remap b*196+n -> b*197+1+n)
  k_gemm<2><<<dim3(3, 196), dim3(256), 0, stream>>>(patches, patch_wb, patch_b, nullptr, h, 384, 768, 1);

  for (int i = 0; i < 12; i++) {
    k_ln<<<dim3((unsigned)R), dim3(128), 0, stream>>>(h, ln1_g + i * 384, ln1_b + i * 384, xn);
    k_gemm<0><<<dim3(9, 197), dim3(256), 0, stream>>>(xn, qkv_wb + (size_t)i * 1152 * 384,
                                                      qkv_b + i * 1152, qkvb, nullptr, 1152, 384, 0);
    k_attn<<<dim3(768), dim3(256), 0, stream>>>(qkvb, ctxb);
    k_gemm<2><<<dim3(3, 197), dim3(256), 0, stream>>>(ctxb, out_wb + (size_t)i * 384 * 384,
                                                      out_b + i * 384, nullptr, h, 384, 384, 0);
    k_ln<<<dim3((unsigned)R), dim3(128), 0, stream>>>(h, ln2_g + i * 384, ln2_b + i * 384, xn);
    k_gemm<1><<<dim3(12, 197), dim3(256), 0, stream>>>(xn, fc1_wb + (size_t)i * 1536 * 384,
                                                       fc1_b + i * 1536, hidb, nullptr, 1536, 384, 0);
    k_gemm<2><<<dim3(3, 197), dim3(256), 0, stream>>>(hidb, fc2_wb + (size_t)i * 384 * 1536,
                                                      fc2_b + i * 384, nullptr, h, 384, 1536, 0);
  }
  k_head<<<dim3(128), dim3(128), 0, stream>>>(h, lnf_g, lnf_b, head_w, out);
}

// Round 7
// 3457.419 us; speedup vs baseline: 1.4672x; 1.0017x over previous
//
#include <hip/hip_runtime.h>
#include <hip/hip_bf16.h>

// ViT-S/16 forward, B=128. Inputs/outputs fp32 (per reference). Internal:
// weights+activations bf16 for MFMA, residual stream fp32, LN/softmax fp32.
// R5: k_gemm = double-buffered LDS (one barrier/iter) + XOR chunk-swizzle.
// R11: XCD-aware bijective block swizzle (T1/m204) -> A-panel L2 reuse
// (fc1 FETCH 24 MB ~= ideal). 3463 us.
// R12: (a) gelu erf -> branch-free tanh form (fc1 epilogue was ~3000 VALU
// cyc/thread of divergent ocml erff; VALUBusy 39%); (b) qkv stored
// head-major [which][b*6+hd][s][64] so k_attn's Q/K loads are dense 128-B
// rows instead of 2304-B-strided 16-B fragments (4x fewer L2 transactions).

#define S_ 197
#define D_ 384
#define BATCH 128

using bf16 = __hip_bfloat16;
typedef __attribute__((ext_vector_type(8))) __bf16 bf16x8;
typedef __attribute__((ext_vector_type(4))) float f32x4;

#if __has_builtin(__builtin_amdgcn_global_load_lds)
#define HAVE_GLL 1
__device__ __forceinline__ void gll16(const bf16* g, __bf16* l) {
  __builtin_amdgcn_global_load_lds(
      (const __attribute__((address_space(1))) void*)g,
      (__attribute__((address_space(3))) void*)l, 16, 0, 0);
}
#else
#define HAVE_GLL 0
#endif

// fp32 -> bf16 (RN), 4 elements/thread. n must be a multiple of 4.
__global__ __launch_bounds__(256) void k_f2b(const float* __restrict__ src,
                                             bf16* __restrict__ dst, int n4) {
  int i = blockIdx.x * 256 + threadIdx.x;
  if (i >= n4) return;
  float4 v = ((const float4*)src)[i];
  bf16 o[4] = {__float2bfloat16(v.x), __float2bfloat16(v.y),
               __float2bfloat16(v.z), __float2bfloat16(v.w)};
  ((uint2*)dst)[i] = *(uint2*)o;
}

__global__ __launch_bounds__(256) void k_embed_init(const float* __restrict__ cls,
                                                    const float* __restrict__ pos,
                                                    float* __restrict__ h) {
  int idx = blockIdx.x * 256 + threadIdx.x;
  if (idx >= BATCH * S_ * D_) return;
  int d = idx % D_;
  int s = (idx / D_) % S_;
  float v = pos[s * D_ + d];
  if (s == 0) v += cls[d];
  h[idx] = v;
}

__global__ __launch_bounds__(256) void k_patchify(const float* __restrict__ x,
                                                  bf16* __restrict__ patches) {
  int idx = blockIdx.x * 256 + threadIdx.x;
  if (idx >= BATCH * 196 * 768) return;
  int f = idx % 768;
  int n = (idx / 768) % 196;
  int b = idx / (768 * 196);
  int c = f >> 8, rem = f & 255, dy = rem >> 4, dx = rem & 15;
  int py = n / 14, px = n % 14;
  patches[idx] = __float2bfloat16(
      x[(((size_t)b * 3 + c) * 224 + py * 16 + dy) * 224 + px * 16 + dx]);
}

// out[M,N] = X[M,K] @ W[N,K]^T + bias.  Grid: (N/128, M/128), 256 threads.
// MODE 0: out=bf16(v)                  (row-major [M,N])
// MODE 1: out=bf16(gelu_tanh(v))       (row-major [M,N])
// MODE 2: res(f32) += v                (remap!=0: row r -> r + r/196 + 1)
// MODE 3: out=bf16(v) head-major QKV:  col=(which*384+hd*64+d), row=(b,s) ->
//         out[((which*768 + b*6 + hd)*197 + s)*64 + d]
// XCD swizzle (T1/m204): bijective remap so all n-tiles of an m-row run
// consecutively on ONE XCD -> A-panel fetched once, L2-served after.
// LDS layout: row stride 32 elems, XOR chunk-swizzle (2-way alias = free).
// Double-buffered: prefetch k+1 while computing k.
template <int MODE>
__global__ __launch_bounds__(256, 4) void k_gemm(const bf16* __restrict__ X,
                                                 const bf16* __restrict__ W,
                                                 const float* __restrict__ bias,
                                                 bf16* __restrict__ out,
                                                 float* __restrict__ res,
                                                 int N, int K, int remap) {
  __shared__ __align__(16) __bf16 As[2][128 * 32];
  __shared__ __align__(16) __bf16 Bs[2][128 * 32];
  const int tid = threadIdx.x;

  // --- XCD-aware bijective swizzle (T1/m204) ---
  const int gx = gridDim.x;
  const int nwg = gx * gridDim.y;
  const int lid = blockIdx.y * gx + blockIdx.x;
  const int xcd = lid & 7, sseq = lid >> 3;
  const int q8 = nwg >> 3, r8 = nwg & 7;
  const int start = xcd * q8 + (xcd < r8 ? xcd : r8);
  const int wgid = start + sseq;
  const int m0 = (wgid / gx) * 128, n0 = (wgid % gx) * 128;

  const int lane = tid & 63, w = tid >> 6;
  const int wr = w >> 1, wc = w & 1;
  const int l16 = lane & 15, quad = lane >> 4;
  f32x4 acc[4][4] = {};

  const int srow = w * 32 + (lane >> 2);
  const int scol = (((lane & 3) ^ ((lane >> 3) & 3)) << 3);
  const bf16* Ag = X + (size_t)(m0 + srow) * K + scol;
  const bf16* Bg = W + (size_t)(n0 + srow) * K + scol;
  const int ldsW = w * 32 * 32;  // wave-uniform LDS base offset (elems)

  const int jx8 = ((quad ^ ((l16 >> 1) & 3)) << 3);
  const int aoff = (wr * 64 + l16) * 32 + jx8;
  const int boff = (wc * 64 + l16) * 32 + jx8;

#if HAVE_GLL
#define STAGE(buf, k0)                                         \
  do {                                                         \
    gll16(Ag + (k0), &As[buf][ldsW]);                          \
    gll16(Ag + (k0) + (size_t)16 * K, &As[buf][ldsW + 512]);   \
    gll16(Bg + (k0), &Bs[buf][ldsW]);                          \
    gll16(Bg + (k0) + (size_t)16 * K, &Bs[buf][ldsW + 512]);   \
  } while (0)
#else
#define STAGE(buf, k0)                                                        \
  do {                                                                        \
    *(uint4*)(&As[buf][ldsW + (lane >> 2) * 32 + (lane & 3) * 8]) =           \
        *(const uint4*)(Ag + (k0));                                           \
    *(uint4*)(&As[buf][ldsW + 512 + (lane >> 2) * 32 + (lane & 3) * 8]) =     \
        *(const uint4*)(Ag + (k0) + (size_t)16 * K);                          \
    *(uint4*)(&Bs[buf][ldsW + (lane >> 2) * 32 + (lane & 3) * 8]) =           \
        *(const uint4*)(Bg + (k0));                                           \
    *(uint4*)(&Bs[buf][ldsW + 512 + (lane >> 2) * 32 + (lane & 3) * 8]) =     \
        *(const uint4*)(Bg + (k0) + (size_t)16 * K);                          \
  } while (0)
#endif

  STAGE(0, 0);
  __syncthreads();
  for (int k0 = 0; k0 < K; k0 += 32) {
    const int cb = (k0 >> 5) & 1;
    if (k0 + 32 < K) STAGE(cb ^ 1, k0 + 32);
    bf16x8 av[4], bv[4];
#pragma unroll
    for (int i = 0; i < 4; i++)
      av[i] = *(const bf16x8*)(&As[cb][aoff + i * 512]);
#pragma unroll
    for (int j = 0; j < 4; j++)
      bv[j] = *(const bf16x8*)(&Bs[cb][boff + j * 512]);
#pragma unroll
    for (int i = 0; i < 4; i++)
#pragma unroll
      for (int j = 0; j < 4; j++)
        acc[i][j] = __builtin_amdgcn_mfma_f32_16x16x32_bf16(av[i], bv[j], acc[i][j], 0, 0, 0);
    __syncthreads();
  }
#undef STAGE

  float bvv[4];
#pragma unroll
  for (int j = 0; j < 4; j++)
    bvv[j] = bias[n0 + wc * 64 + j * 16 + l16];
#pragma unroll
  for (int i = 0; i < 4; i++) {
    const int rbase = m0 + wr * 64 + i * 16 + quad * 4;
#pragma unroll
    for (int j = 0; j < 4; j++) {
      const int col = n0 + wc * 64 + j * 16 + l16;
      // MODE 3 per-col decomposition (wave-uniform per j except l16 in d)
      const int which = col / 384;
      const int hd2 = (col >> 6) % 6;
      const int d = col & 63;
#pragma unroll
      for (int r = 0; r < 4; r++) {
        float v = acc[i][j][r] + bvv[j];
        int rw = rbase + r;
        if (MODE == 0) {
          out[(size_t)rw * N + col] = __float2bfloat16(v);
        } else if (MODE == 1) {
          // gelu tanh-form (branch-free): 0.5v(1+tanh(0.79788456 v (1+0.044715 v^2)))
          float t = 0.7978845608f * v * (1.f + 0.044715f * v * v);
          float e = __expf(2.f * t);
          float th = 1.f - 2.f / (e + 1.f);
          out[(size_t)rw * N + col] = __float2bfloat16(0.5f * v * (1.f + th));
        } else if (MODE == 3) {
          int b2 = rw / 197;
          int s = rw - b2 * 197;
          out[((size_t)(which * 768 + b2 * 6 + hd2) * 197 + s) * 64 + d] =
              __float2bfloat16(v);
        } else {
          int hr = remap ? (rw + rw / 196 + 1) : rw;
          res[(size_t)hr * N + col] += v;
        }
      }
    }
  }
}

__global__ __launch_bounds__(128) void k_ln(const float* __restrict__ h,
                                            const float* __restrict__ g,
                                            const float* __restrict__ bt,
                                            bf16* __restrict__ xn) {
  const int r = blockIdx.x, t = threadIdx.x;
  const float* row = h + (size_t)r * D_;
  float x0 = row[t], x1 = row[t + 128], x2 = row[t + 256];
  float s = x0 + x1 + x2;
  float q = x0 * x0 + x1 * x1 + x2 * x2;
#pragma unroll
  for (int o = 32; o; o >>= 1) {
    s += __shfl_xor(s, o);
    q += __shfl_xor(q, o);
  }
  __shared__ float rs[2], rq[2];
  if ((t & 63) == 0) { rs[t >> 6] = s; rq[t >> 6] = q; }
  __syncthreads();
  s = rs[0] + rs[1];
  q = rq[0] + rq[1];
  const float mean = s * (1.f / 384.f);
  const float var = q * (1.f / 384.f) - mean * mean;
  const float rstd = rsqrtf(var + 1e-5f);
  bf16* o = xn + (size_t)r * D_;
  o[t] = __float2bfloat16((x0 - mean) * rstd * g[t] + bt[t]);
  o[t + 128] = __float2bfloat16((x1 - mean) * rstd * g[t + 128] + bt[t + 128]);
  o[t + 256] = __float2bfloat16((x2 - mean) * rstd * g[t + 256] + bt[t + 256]);
}

// MFMA flash attention, head-major QKV input: Q/K/V each [197][64] contiguous
// per (b,head). One block per (b, head), 4 waves; wave owns q-bands
// {w, w+4, ...}: QK^T (13 col-tiles) -> masked softmax -> P to LDS -> P@V.
__global__ __launch_bounds__(256) void k_attn(const bf16* __restrict__ qkv,
                                              bf16* __restrict__ ctx) {
  const int bh = blockIdx.x;
  const int b = bh / 6, hd = bh % 6;
  const bf16* Qg = qkv + (size_t)bh * 12608;           // 197*64
  const bf16* Kg = qkv + (size_t)(768 + bh) * 12608;
  const bf16* Vg = qkv + (size_t)(1536 + bh) * 12608;
  // Vt[d][k] = V[k][d]; stride 232 (116 dw -> 2-way bank alias = free)
  __shared__ __align__(16) __bf16 Vt[64 * 232];
  __shared__ __align__(16) __bf16 Ps[4][16 * 232];
  const int tid = threadIdx.x;
  const int lane = tid & 63, w = tid >> 6;
  const int l16 = lane & 15, quad = lane >> 4;
  const __bf16 z = (__bf16)0.0f;

  // zero Vt pad cols (k = 197..231)
  for (int i = tid; i < 64 * 35; i += 256) {
    int d = i / 35, k = 197 + i % 35;
    Vt[d * 232 + k] = z;
  }
  // stage V transposed (reads are 128-B contiguous rows)
  for (int i = tid; i < S_ * 64; i += 256) {
    int k = i >> 6, d = i & 63;
    Vt[d * 232 + k] = *(const __bf16*)&Vg[(size_t)k * 64 + d];
  }
  // zero own Ps pad cols (208..231)
  for (int i = lane; i < 16 * 24; i += 64) {
    int r = i / 24, c = 208 + i % 24;
    Ps[w][r * 232 + c] = z;
  }
  __syncthreads();

  const bf16x8 zf = {};
  for (int band = w; band < 13; band += 4) {
    // Q A-fragments (row = band*16 + l16), predicated on row < 197
    const int qrow = band * 16 + l16;
    bf16x8 aq0 = zf, aq1 = zf;
    if (qrow < S_) {
      aq0 = *(const bf16x8*)(Qg + (size_t)qrow * 64 + quad * 8);
      aq1 = *(const bf16x8*)(Qg + (size_t)qrow * 64 + 32 + quad * 8);
    }
    // scores: 13 col-tiles of 16
    f32x4 sc[13];
#pragma unroll
    for (int t = 0; t < 13; t++) {
      const int krow = t * 16 + l16;
      bf16x8 bk0 = zf, bk1 = zf;
      if (krow < S_) {
        bk0 = *(const bf16x8*)(Kg + (size_t)krow * 64 + quad * 8);
        bk1 = *(const bf16x8*)(Kg + (size_t)krow * 64 + 32 + quad * 8);
      }
      f32x4 a = {};
      a = __builtin_amdgcn_mfma_f32_16x16x32_bf16(aq0, bk0, a, 0, 0, 0);
      a = __builtin_amdgcn_mfma_f32_16x16x32_bf16(aq1, bk1, a, 0, 0, 0);
      sc[t] = a;
    }
    // scale 1/sqrt(64), mask pad cols (192+l16 >= 197)
#pragma unroll
    for (int t = 0; t < 13; t++)
#pragma unroll
      for (int r = 0; r < 4; r++) sc[t][r] *= 0.125f;
    if (l16 >= 5) {
#pragma unroll
      for (int r = 0; r < 4; r++) sc[12][r] = -1e30f;
    }
    // row max (13 tiles in-reg, then across the 16 lanes of this quad)
    f32x4 mx = sc[0];
#pragma unroll
    for (int t = 1; t < 13; t++)
#pragma unroll
      for (int r = 0; r < 4; r++) mx[r] = fmaxf(mx[r], sc[t][r]);
#pragma unroll
    for (int o = 1; o < 16; o <<= 1)
#pragma unroll
      for (int r = 0; r < 4; r++) mx[r] = fmaxf(mx[r], __shfl_xor(mx[r], o));
    // exp + row sum
    f32x4 sum = {};
#pragma unroll
    for (int t = 0; t < 13; t++)
#pragma unroll
      for (int r = 0; r < 4; r++) {
        float p = __expf(sc[t][r] - mx[r]);
        sc[t][r] = p;
        sum[r] += p;
      }
#pragma unroll
    for (int o = 1; o < 16; o <<= 1)
#pragma unroll
      for (int r = 0; r < 4; r++) sum[r] += __shfl_xor(sum[r], o);
    f32x4 rinv;
#pragma unroll
    for (int r = 0; r < 4; r++) rinv[r] = 1.0f / sum[r];
    // write unnormalized P band (C layout -> LDS); pad cols 197..207 are
    // exact zeros (exp(-1e30-m) underflows to 0)
#pragma unroll
    for (int t = 0; t < 13; t++)
#pragma unroll
      for (int r = 0; r < 4; r++)
        Ps[w][(quad * 4 + r) * 232 + t * 16 + l16] = (__bf16)sc[t][r];
    // P @ V: out cols d = c*16 + l16, k over 224 (7 steps of 32)
    f32x4 oacc[4] = {};
#pragma unroll
    for (int ks = 0; ks < 7; ks++) {
      bf16x8 pa = *(const bf16x8*)&Ps[w][l16 * 232 + ks * 32 + quad * 8];
#pragma unroll
      for (int c = 0; c < 4; c++) {
        bf16x8 bv = *(const bf16x8*)&Vt[(c * 16 + l16) * 232 + ks * 32 + quad * 8];
        oacc[c] = __builtin_amdgcn_mfma_f32_16x16x32_bf16(pa, bv, oacc[c], 0, 0, 0);
      }
    }
    // epilogue: rows band*16 + quad*4 + r (guarded), cols hd*64 + c*16 + l16
    const int orow = band * 16 + quad * 4;
#pragma unroll
    for (int c = 0; c < 4; c++)
#pragma unroll
      for (int r = 0; r < 4; r++) {
        const int rw = orow + r;
        if (rw < S_)
          ctx[((size_t)b * S_ + rw) * D_ + hd * 64 + c * 16 + l16] =
              __float2bfloat16(oacc[c][r] * rinv[r]);
      }
  }
}

__global__ __launch_bounds__(128) void k_head(const float* __restrict__ h,
                                              const float* __restrict__ g,
                                              const float* __restrict__ bt,
                                              const float* __restrict__ hw,
                                              float* __restrict__ out) {
  const int b = blockIdx.x, t = threadIdx.x;
  const float* row = h + (size_t)b * S_ * D_;
  float x0 = row[t], x1 = row[t + 128], x2 = row[t + 256];
  float s = x0 + x1 + x2;
  float q = x0 * x0 + x1 * x1 + x2 * x2;
#pragma unroll
  for (int o = 32; o; o >>= 1) {
    s += __shfl_xor(s, o);
    q += __shfl_xor(q, o);
  }
  __shared__ float rs[2], rq[2];
  if ((t & 63) == 0) { rs[t >> 6] = s; rq[t >> 6] = q; }
  __syncthreads();
  s = rs[0] + rs[1];
  q = rq[0] + rq[1];
  const float mean = s * (1.f / 384.f);
  const float var = q * (1.f / 384.f) - mean * mean;
  const float rstd = rsqrtf(var + 1e-5f);
  __shared__ float clsn[384];
  clsn[t] = (x0 - mean) * rstd * g[t] + bt[t];
  clsn[t + 128] = (x1 - mean) * rstd * g[t + 128] + bt[t + 128];
  clsn[t + 256] = (x2 - mean) * rstd * g[t + 256] + bt[t + 256];
  __syncthreads();
  if (t < 100) {
    const float* wr = hw + (size_t)t * D_;
    float a = 0.f;
    for (int d = 0; d < 384; d++) a += clsn[d] * wr[d];
    out[b * 100 + t] = a;
  }
}

extern "C" void kernel_launch(void* const* d_in, const int* in_sizes, int n_in,
                              void* d_out, int out_size, void* d_ws, size_t ws_size,
                              hipStream_t stream) {
  (void)in_sizes; (void)n_in; (void)out_size; (void)ws_size;
  const float* x       = (const float*)d_in[0];
  const float* patch_w = (const float*)d_in[1];
  const float* patch_b = (const float*)d_in[2];
  const float* cls_tok = (const float*)d_in[3];
  const float* pos_emb = (const float*)d_in[4];
  const float* ln1_g   = (const float*)d_in[5];
  const float* ln1_b   = (const float*)d_in[6];
  const float* qkv_w   = (const float*)d_in[7];
  const float* qkv_b   = (const float*)d_in[8];
  const float* out_w   = (const float*)d_in[9];
  const float* out_b   = (const float*)d_in[10];
  const float* ln2_g   = (const float*)d_in[11];
  const float* ln2_b   = (const float*)d_in[12];
  const float* fc1_w   = (const float*)d_in[13];
  const float* fc1_b   = (const float*)d_in[14];
  const float* fc2_w   = (const float*)d_in[15];
  const float* fc2_b   = (const float*)d_in[16];
  const float* lnf_g   = (const float*)d_in[17];
  const float* lnf_b   = (const float*)d_in[18];
  const float* head_w  = (const float*)d_in[19];
  float* out = (float*)d_out;

  const size_t R = (size_t)BATCH * S_;  // 25216 token rows
  char* p = (char*)d_ws;
  float* h  = (float*)p; p += R * 384 * 4;       // fp32 residual
  bf16* xn  = (bf16*)p;  p += R * 384 * 2;       // LN output
  bf16* u   = (bf16*)p;  p += R * 1536 * 2;      // union: qkvb|ctxb / hid / patches
  bf16* qkvb = u;                                 // 3*768*197*64 = R*1152
  bf16* ctxb = u + R * 1152;                      // R*384
  bf16* hidb = u;                                 // R*1536 (qkv/ctx dead by then)
  bf16* patches = u;                              // 25088*768 (pre-loop only)
  bf16* wb  = (bf16*)p;                           // bf16 weights
  bf16* patch_wb = wb;                            // 768*384
  bf16* qkv_wb   = patch_wb + 294912;             // 12*1152*384
  bf16* out_wb   = qkv_wb + 5308416;              // 12*384*384
  bf16* fc1_wb   = out_wb + 1769472;              // 12*1536*384
  bf16* fc2_wb   = fc1_wb + 7077888;              // 12*384*1536

  // weight conversion fp32 -> bf16 (same work every launch; graph-safe)
  k_f2b<<<dim3((294912 / 4 + 255) / 256), dim3(256), 0, stream>>>(patch_w, patch_wb, 294912 / 4);
  k_f2b<<<dim3((5308416 / 4 + 255) / 256), dim3(256), 0, stream>>>(qkv_w, qkv_wb, 5308416 / 4);
  k_f2b<<<dim3((1769472 / 4 + 255) / 256), dim3(256), 0, stream>>>(out_w, out_wb, 1769472 / 4);
  k_f2b<<<dim3((7077888 / 4 + 255) / 256), dim3(256), 0, stream>>>(fc1_w, fc1_wb, 7077888 / 4);
  k_f2b<<<dim3((7077888 / 4 + 255) / 256), dim3(256), 0, stream>>>(fc2_w, fc2_wb, 7077888 / 4);

  k_embed_init<<<dim3((BATCH * S_ * D_) / 256), dim3(256), 0, stream>>>(cls_tok, pos_emb, h);
  k_patchify<<<dim3((BATCH * 196 * 768) / 256), dim3(256), 0, stream>>>(x, patches);
  // tok = patches @ patch_w^T + patch_b, accumulated into h (row remap b*196+n -> b*197+1+n)
  k_gemm<2><<<dim3(3, 196), dim3(256), 0, stream>>>(patches, patch_wb, patch_b, nullptr, h, 384, 768, 1);

  for (int i = 0; i < 12; i++) {
    k_ln<<<dim3((unsigned)R), dim3(128), 0, stream>>>(h, ln1_g + i * 384, ln1_b + i * 384, xn);
    // qkv in head-major layout (MODE 3)
    k_gemm<3><<<dim3(9, 197), dim3(256), 0, stream>>>(xn, qkv_wb + (size_t)i * 1152 * 384,
                                                      qkv_b + i * 1152, qkvb, nullptr, 1152, 384, 0);
    k_attn<<<dim3(768), dim3(256), 0, stream>>>(qkvb, ctxb);
    k_gemm<2><<<dim3(3, 197), dim3(256), 0, stream>>>(ctxb, out_wb + (size_t)i * 384 * 384,
                                                      out_b + i * 384, nullptr, h, 384, 384, 0);
    k_ln<<<dim3((unsigned)R), dim3(128), 0, stream>>>(h, ln2_g + i * 384, ln2_b + i * 384, xn);
    k_gemm<1><<<dim3(12, 197), dim3(256), 0, stream>>>(xn, fc1_wb + (size_t)i * 1536 * 384,
                                                       fc1_b + i * 1536, hidb, nullptr, 1536, 384, 0);
    k_gemm<2><<<dim3(3, 197), dim3(256), 0, stream>>>(hidb, fc2_wb + (size_t)i * 384 * 1536,
                                                      fc2_b + i * 384, nullptr, h, 384, 1536, 0);
  }
  k_head<<<dim3(128), dim3(128), 0, stream>>>(h, lnf_g, lnf_b, head_w, out);
}

// Round 8
// 3227.715 us; speedup vs baseline: 1.5717x; 1.0712x over previous
//
#include <hip/hip_runtime.h>
#include <hip/hip_bf16.h>

// ViT-S/16 forward, B=128. Inputs/outputs fp32 (per reference). Internal:
// weights+activations bf16 for MFMA, residual stream fp32, LN/softmax fp32.
// R11: XCD-aware bijective block swizzle (T1/m204) -> A-panel L2 reuse. 3463.
// R12: gelu tanh-form + head-major QKV. Neutral (3457); fc1 FETCH is ideal,
// MfmaUtil 18% / HBM 18% / Occupancy 33% -> latency-bound, not pipe-bound.
// R13: 8-wave (512-thread) GEMM blocks. Same 128x128 tile + 32KB LDS; each
// wave now computes 64x32 (acc[4][2], 8 MFMA/iter), staging is 1 gll16 per
// matrix per wave. launch_bounds(512,6) -> 3 blocks x 8 waves = 24 waves/CU
// (75%) where grid allows; fc2/outproj (591 blocks) go 9.2 -> 18.5 waves/CU.
// Swizzle algebra unchanged (wave row-bases stay multiples of 8).

#define S_ 197
#define D_ 384
#define BATCH 128

using bf16 = __hip_bfloat16;
typedef __attribute__((ext_vector_type(8))) __bf16 bf16x8;
typedef __attribute__((ext_vector_type(4))) float f32x4;

#if __has_builtin(__builtin_amdgcn_global_load_lds)
#define HAVE_GLL 1
__device__ __forceinline__ void gll16(const bf16* g, __bf16* l) {
  __builtin_amdgcn_global_load_lds(
      (const __attribute__((address_space(1))) void*)g,
      (__attribute__((address_space(3))) void*)l, 16, 0, 0);
}
#else
#define HAVE_GLL 0
#endif

// fp32 -> bf16 (RN), 4 elements/thread. n must be a multiple of 4.
__global__ __launch_bounds__(256) void k_f2b(const float* __restrict__ src,
                                             bf16* __restrict__ dst, int n4) {
  int i = blockIdx.x * 256 + threadIdx.x;
  if (i >= n4) return;
  float4 v = ((const float4*)src)[i];
  bf16 o[4] = {__float2bfloat16(v.x), __float2bfloat16(v.y),
               __float2bfloat16(v.z), __float2bfloat16(v.w)};
  ((uint2*)dst)[i] = *(uint2*)o;
}

__global__ __launch_bounds__(256) void k_embed_init(const float* __restrict__ cls,
                                                    const float* __restrict__ pos,
                                                    float* __restrict__ h) {
  int idx = blockIdx.x * 256 + threadIdx.x;
  if (idx >= BATCH * S_ * D_) return;
  int d = idx % D_;
  int s = (idx / D_) % S_;
  float v = pos[s * D_ + d];
  if (s == 0) v += cls[d];
  h[idx] = v;
}

__global__ __launch_bounds__(256) void k_patchify(const float* __restrict__ x,
                                                  bf16* __restrict__ patches) {
  int idx = blockIdx.x * 256 + threadIdx.x;
  if (idx >= BATCH * 196 * 768) return;
  int f = idx % 768;
  int n = (idx / 768) % 196;
  int b = idx / (768 * 196);
  int c = f >> 8, rem = f & 255, dy = rem >> 4, dx = rem & 15;
  int py = n / 14, px = n % 14;
  patches[idx] = __float2bfloat16(
      x[(((size_t)b * 3 + c) * 224 + py * 16 + dy) * 224 + px * 16 + dx]);
}

// out[M,N] = X[M,K] @ W[N,K]^T + bias.  Grid: (N/128, M/128), 512 threads.
// 8 waves in 2x4: wave tile 64 rows x 32 cols, acc[4][2].
// MODE 0: out=bf16(v)                  (row-major [M,N])
// MODE 1: out=bf16(gelu_tanh(v))       (row-major [M,N])
// MODE 2: res(f32) += v                (remap!=0: row r -> r + r/196 + 1)
// MODE 3: out=bf16(v) head-major QKV:  col=(which*384+hd*64+d), row=(b,s) ->
//         out[((which*768 + b*6 + hd)*197 + s)*64 + d]
// XCD swizzle (T1/m204): all n-tiles of an m-row on one XCD back-to-back.
// LDS: row stride 32 elems, XOR chunk-swizzle; double-buffered.
template <int MODE>
__global__ __launch_bounds__(512, 6) void k_gemm(const bf16* __restrict__ X,
                                                 const bf16* __restrict__ W,
                                                 const float* __restrict__ bias,
                                                 bf16* __restrict__ out,
                                                 float* __restrict__ res,
                                                 int N, int K, int remap) {
  __shared__ __align__(16) __bf16 As[2][128 * 32];
  __shared__ __align__(16) __bf16 Bs[2][128 * 32];
  const int tid = threadIdx.x;

  // --- XCD-aware bijective swizzle (T1/m204) ---
  const int gx = gridDim.x;
  const int nwg = gx * gridDim.y;
  const int lid = blockIdx.y * gx + blockIdx.x;
  const int xcd = lid & 7, sseq = lid >> 3;
  const int q8 = nwg >> 3, r8 = nwg & 7;
  const int start = xcd * q8 + (xcd < r8 ? xcd : r8);
  const int wgid = start + sseq;
  const int m0 = (wgid / gx) * 128, n0 = (wgid % gx) * 128;

  const int lane = tid & 63, w = tid >> 6;     // w in 0..7
  const int wr = w >> 2, wc = w & 3;           // 2x4 wave grid
  const int l16 = lane & 15, quad = lane >> 4;
  f32x4 acc[4][2] = {};

  // staging: wave w covers tile rows w*16..w*16+15 (1 gll16/matrix/wave).
  // lane -> slot row (lane>>2), slot chunk (lane&3); global chunk swizzled:
  // c = (lane&3) ^ ((lane>>3)&3)   [(row>>1)&3 == (lane>>3)&3, w*8 = 0 mod 4]
  const int srow = w * 16 + (lane >> 2);
  const int scol = (((lane & 3) ^ ((lane >> 3) & 3)) << 3);
  const bf16* Ag = X + (size_t)(m0 + srow) * K + scol;
  const bf16* Bg = W + (size_t)(n0 + srow) * K + scol;
  const int ldsW = w * 512;  // wave-uniform LDS base offset (elems)

  // fragment reads: row r needs global chunk `quad`, at slot chunk
  // quad ^ ((l16>>1)&3)   [row bases wr*64, wc*32 are multiples of 8]
  const int jx8 = ((quad ^ ((l16 >> 1) & 3)) << 3);
  const int aoff = (wr * 64 + l16) * 32 + jx8;
  const int boff = (wc * 32 + l16) * 32 + jx8;

#if HAVE_GLL
#define STAGE(buf, k0)                 \
  do {                                 \
    gll16(Ag + (k0), &As[buf][ldsW]);  \
    gll16(Bg + (k0), &Bs[buf][ldsW]);  \
  } while (0)
#else
#define STAGE(buf, k0)                                                \
  do {                                                                \
    *(uint4*)(&As[buf][ldsW + (lane >> 2) * 32 + (lane & 3) * 8]) =   \
        *(const uint4*)(Ag + (k0));                                   \
    *(uint4*)(&Bs[buf][ldsW + (lane >> 2) * 32 + (lane & 3) * 8]) =   \
        *(const uint4*)(Bg + (k0));                                   \
  } while (0)
#endif

  STAGE(0, 0);
  __syncthreads();
  for (int k0 = 0; k0 < K; k0 += 32) {
    const int cb = (k0 >> 5) & 1;
    if (k0 + 32 < K) STAGE(cb ^ 1, k0 + 32);
    bf16x8 av[4], bv[2];
#pragma unroll
    for (int i = 0; i < 4; i++)
      av[i] = *(const bf16x8*)(&As[cb][aoff + i * 512]);
#pragma unroll
    for (int j = 0; j < 2; j++)
      bv[j] = *(const bf16x8*)(&Bs[cb][boff + j * 512]);
#pragma unroll
    for (int i = 0; i < 4; i++)
#pragma unroll
      for (int j = 0; j < 2; j++)
        acc[i][j] = __builtin_amdgcn_mfma_f32_16x16x32_bf16(av[i], bv[j], acc[i][j], 0, 0, 0);
    __syncthreads();
  }
#undef STAGE

  float bvv[2];
#pragma unroll
  for (int j = 0; j < 2; j++)
    bvv[j] = bias[n0 + wc * 32 + j * 16 + l16];
#pragma unroll
  for (int i = 0; i < 4; i++) {
    const int rbase = m0 + wr * 64 + i * 16 + quad * 4;
#pragma unroll
    for (int j = 0; j < 2; j++) {
      const int col = n0 + wc * 32 + j * 16 + l16;
      // MODE 3 per-col decomposition
      const int which = col / 384;
      const int hd2 = (col >> 6) % 6;
      const int d = col & 63;
#pragma unroll
      for (int r = 0; r < 4; r++) {
        float v = acc[i][j][r] + bvv[j];
        int rw = rbase + r;
        if (MODE == 0) {
          out[(size_t)rw * N + col] = __float2bfloat16(v);
        } else if (MODE == 1) {
          // gelu tanh-form (branch-free)
          float t = 0.7978845608f * v * (1.f + 0.044715f * v * v);
          float e = __expf(2.f * t);
          float th = 1.f - 2.f / (e + 1.f);
          out[(size_t)rw * N + col] = __float2bfloat16(0.5f * v * (1.f + th));
        } else if (MODE == 3) {
          int b2 = rw / 197;
          int s = rw - b2 * 197;
          out[((size_t)(which * 768 + b2 * 6 + hd2) * 197 + s) * 64 + d] =
              __float2bfloat16(v);
        } else {
          int hr = remap ? (rw + rw / 196 + 1) : rw;
          res[(size_t)hr * N + col] += v;
        }
      }
    }
  }
}

__global__ __launch_bounds__(128) void k_ln(const float* __restrict__ h,
                                            const float* __restrict__ g,
                                            const float* __restrict__ bt,
                                            bf16* __restrict__ xn) {
  const int r = blockIdx.x, t = threadIdx.x;
  const float* row = h + (size_t)r * D_;
  float x0 = row[t], x1 = row[t + 128], x2 = row[t + 256];
  float s = x0 + x1 + x2;
  float q = x0 * x0 + x1 * x1 + x2 * x2;
#pragma unroll
  for (int o = 32; o; o >>= 1) {
    s += __shfl_xor(s, o);
    q += __shfl_xor(q, o);
  }
  __shared__ float rs[2], rq[2];
  if ((t & 63) == 0) { rs[t >> 6] = s; rq[t >> 6] = q; }
  __syncthreads();
  s = rs[0] + rs[1];
  q = rq[0] + rq[1];
  const float mean = s * (1.f / 384.f);
  const float var = q * (1.f / 384.f) - mean * mean;
  const float rstd = rsqrtf(var + 1e-5f);
  bf16* o = xn + (size_t)r * D_;
  o[t] = __float2bfloat16((x0 - mean) * rstd * g[t] + bt[t]);
  o[t + 128] = __float2bfloat16((x1 - mean) * rstd * g[t + 128] + bt[t + 128]);
  o[t + 256] = __float2bfloat16((x2 - mean) * rstd * g[t + 256] + bt[t + 256]);
}

// MFMA flash attention, head-major QKV input: Q/K/V each [197][64] contiguous
// per (b,head). One block per (b, head), 4 waves; wave owns q-bands
// {w, w+4, ...}: QK^T (13 col-tiles) -> masked softmax -> P to LDS -> P@V.
__global__ __launch_bounds__(256) void k_attn(const bf16* __restrict__ qkv,
                                              bf16* __restrict__ ctx) {
  const int bh = blockIdx.x;
  const int b = bh / 6, hd = bh % 6;
  const bf16* Qg = qkv + (size_t)bh * 12608;           // 197*64
  const bf16* Kg = qkv + (size_t)(768 + bh) * 12608;
  const bf16* Vg = qkv + (size_t)(1536 + bh) * 12608;
  // Vt[d][k] = V[k][d]; stride 232 (116 dw -> 2-way bank alias = free)
  __shared__ __align__(16) __bf16 Vt[64 * 232];
  __shared__ __align__(16) __bf16 Ps[4][16 * 232];
  const int tid = threadIdx.x;
  const int lane = tid & 63, w = tid >> 6;
  const int l16 = lane & 15, quad = lane >> 4;
  const __bf16 z = (__bf16)0.0f;

  // zero Vt pad cols (k = 197..231)
  for (int i = tid; i < 64 * 35; i += 256) {
    int d = i / 35, k = 197 + i % 35;
    Vt[d * 232 + k] = z;
  }
  // stage V transposed (reads are 128-B contiguous rows)
  for (int i = tid; i < S_ * 64; i += 256) {
    int k = i >> 6, d = i & 63;
    Vt[d * 232 + k] = *(const __bf16*)&Vg[(size_t)k * 64 + d];
  }
  // zero own Ps pad cols (208..231)
  for (int i = lane; i < 16 * 24; i += 64) {
    int r = i / 24, c = 208 + i % 24;
    Ps[w][r * 232 + c] = z;
  }
  __syncthreads();

  const bf16x8 zf = {};
  for (int band = w; band < 13; band += 4) {
    // Q A-fragments (row = band*16 + l16), predicated on row < 197
    const int qrow = band * 16 + l16;
    bf16x8 aq0 = zf, aq1 = zf;
    if (qrow < S_) {
      aq0 = *(const bf16x8*)(Qg + (size_t)qrow * 64 + quad * 8);
      aq1 = *(const bf16x8*)(Qg + (size_t)qrow * 64 + 32 + quad * 8);
    }
    // scores: 13 col-tiles of 16
    f32x4 sc[13];
#pragma unroll
    for (int t = 0; t < 13; t++) {
      const int krow = t * 16 + l16;
      bf16x8 bk0 = zf, bk1 = zf;
      if (krow < S_) {
        bk0 = *(const bf16x8*)(Kg + (size_t)krow * 64 + quad * 8);
        bk1 = *(const bf16x8*)(Kg + (size_t)krow * 64 + 32 + quad * 8);
      }
      f32x4 a = {};
      a = __builtin_amdgcn_mfma_f32_16x16x32_bf16(aq0, bk0, a, 0, 0, 0);
      a = __builtin_amdgcn_mfma_f32_16x16x32_bf16(aq1, bk1, a, 0, 0, 0);
      sc[t] = a;
    }
    // scale 1/sqrt(64), mask pad cols (192+l16 >= 197)
#pragma unroll
    for (int t = 0; t < 13; t++)
#pragma unroll
      for (int r = 0; r < 4; r++) sc[t][r] *= 0.125f;
    if (l16 >= 5) {
#pragma unroll
      for (int r = 0; r < 4; r++) sc[12][r] = -1e30f;
    }
    // row max (13 tiles in-reg, then across the 16 lanes of this quad)
    f32x4 mx = sc[0];
#pragma unroll
    for (int t = 1; t < 13; t++)
#pragma unroll
      for (int r = 0; r < 4; r++) mx[r] = fmaxf(mx[r], sc[t][r]);
#pragma unroll
    for (int o = 1; o < 16; o <<= 1)
#pragma unroll
      for (int r = 0; r < 4; r++) mx[r] = fmaxf(mx[r], __shfl_xor(mx[r], o));
    // exp + row sum
    f32x4 sum = {};
#pragma unroll
    for (int t = 0; t < 13; t++)
#pragma unroll
      for (int r = 0; r < 4; r++) {
        float p = __expf(sc[t][r] - mx[r]);
        sc[t][r] = p;
        sum[r] += p;
      }
#pragma unroll
    for (int o = 1; o < 16; o <<= 1)
#pragma unroll
      for (int r = 0; r < 4; r++) sum[r] += __shfl_xor(sum[r], o);
    f32x4 rinv;
#pragma unroll
    for (int r = 0; r < 4; r++) rinv[r] = 1.0f / sum[r];
    // write unnormalized P band (C layout -> LDS); pad cols 197..207 are
    // exact zeros (exp(-1e30-m) underflows to 0)
#pragma unroll
    for (int t = 0; t < 13; t++)
#pragma unroll
      for (int r = 0; r < 4; r++)
        Ps[w][(quad * 4 + r) * 232 + t * 16 + l16] = (__bf16)sc[t][r];
    // P @ V: out cols d = c*16 + l16, k over 224 (7 steps of 32)
    f32x4 oacc[4] = {};
#pragma unroll
    for (int ks = 0; ks < 7; ks++) {
      bf16x8 pa = *(const bf16x8*)&Ps[w][l16 * 232 + ks * 32 + quad * 8];
#pragma unroll
      for (int c = 0; c < 4; c++) {
        bf16x8 bv = *(const bf16x8*)&Vt[(c * 16 + l16) * 232 + ks * 32 + quad * 8];
        oacc[c] = __builtin_amdgcn_mfma_f32_16x16x32_bf16(pa, bv, oacc[c], 0, 0, 0);
      }
    }
    // epilogue: rows band*16 + quad*4 + r (guarded), cols hd*64 + c*16 + l16
    const int orow = band * 16 + quad * 4;
#pragma unroll
    for (int c = 0; c < 4; c++)
#pragma unroll
      for (int r = 0; r < 4; r++) {
        const int rw = orow + r;
        if (rw < S_)
          ctx[((size_t)b * S_ + rw) * D_ + hd * 64 + c * 16 + l16] =
              __float2bfloat16(oacc[c][r] * rinv[r]);
      }
  }
}

__global__ __launch_bounds__(128) void k_head(const float* __restrict__ h,
                                              const float* __restrict__ g,
                                              const float* __restrict__ bt,
                                              const float* __restrict__ hw,
                                              float* __restrict__ out) {
  const int b = blockIdx.x, t = threadIdx.x;
  const float* row = h + (size_t)b * S_ * D_;
  float x0 = row[t], x1 = row[t + 128], x2 = row[t + 256];
  float s = x0 + x1 + x2;
  float q = x0 * x0 + x1 * x1 + x2 * x2;
#pragma unroll
  for (int o = 32; o; o >>= 1) {
    s += __shfl_xor(s, o);
    q += __shfl_xor(q, o);
  }
  __shared__ float rs[2], rq[2];
  if ((t & 63) == 0) { rs[t >> 6] = s; rq[t >> 6] = q; }
  __syncthreads();
  s = rs[0] + rs[1];
  q = rq[0] + rq[1];
  const float mean = s * (1.f / 384.f);
  const float var = q * (1.f / 384.f) - mean * mean;
  const float rstd = rsqrtf(var + 1e-5f);
  __shared__ float clsn[384];
  clsn[t] = (x0 - mean) * rstd * g[t] + bt[t];
  clsn[t + 128] = (x1 - mean) * rstd * g[t + 128] + bt[t + 128];
  clsn[t + 256] = (x2 - mean) * rstd * g[t + 256] + bt[t + 256];
  __syncthreads();
  if (t < 100) {
    const float* wr = hw + (size_t)t * D_;
    float a = 0.f;
    for (int d = 0; d < 384; d++) a += clsn[d] * wr[d];
    out[b * 100 + t] = a;
  }
}

extern "C" void kernel_launch(void* const* d_in, const int* in_sizes, int n_in,
                              void* d_out, int out_size, void* d_ws, size_t ws_size,
                              hipStream_t stream) {
  (void)in_sizes; (void)n_in; (void)out_size; (void)ws_size;
  const float* x       = (const float*)d_in[0];
  const float* patch_w = (const float*)d_in[1];
  const float* patch_b = (const float*)d_in[2];
  const float* cls_tok = (const float*)d_in[3];
  const float* pos_emb = (const float*)d_in[4];
  const float* ln1_g   = (const float*)d_in[5];
  const float* ln1_b   = (const float*)d_in[6];
  const float* qkv_w   = (const float*)d_in[7];
  const float* qkv_b   = (const float*)d_in[8];
  const float* out_w   = (const float*)d_in[9];
  const float* out_b   = (const float*)d_in[10];
  const float* ln2_g   = (const float*)d_in[11];
  const float* ln2_b   = (const float*)d_in[12];
  const float* fc1_w   = (const float*)d_in[13];
  const float* fc1_b   = (const float*)d_in[14];
  const float* fc2_w   = (const float*)d_in[15];
  const float* fc2_b   = (const float*)d_in[16];
  const float* lnf_g   = (const float*)d_in[17];
  const float* lnf_b   = (const float*)d_in[18];
  const float* head_w  = (const float*)d_in[19];
  float* out = (float*)d_out;

  const size_t R = (size_t)BATCH * S_;  // 25216 token rows
  char* p = (char*)d_ws;
  float* h  = (float*)p; p += R * 384 * 4;       // fp32 residual
  bf16* xn  = (bf16*)p;  p += R * 384 * 2;       // LN output
  bf16* u   = (bf16*)p;  p += R * 1536 * 2;      // union: qkvb|ctxb / hid / patches
  bf16* qkvb = u;                                 // 3*768*197*64 = R*1152
  bf16* ctxb = u + R * 1152;                      // R*384
  bf16* hidb = u;                                 // R*1536 (qkv/ctx dead by then)
  bf16* patches = u;                              // 25088*768 (pre-loop only)
  bf16* wb  = (bf16*)p;                           // bf16 weights
  bf16* patch_wb = wb;                            // 768*384
  bf16* qkv_wb   = patch_wb + 294912;             // 12*1152*384
  bf16* out_wb   = qkv_wb + 5308416;              // 12*384*384
  bf16* fc1_wb   = out_wb + 1769472;              // 12*1536*384
  bf16* fc2_wb   = fc1_wb + 7077888;              // 12*384*1536

  // weight conversion fp32 -> bf16 (same work every launch; graph-safe)
  k_f2b<<<dim3((294912 / 4 + 255) / 256), dim3(256), 0, stream>>>(patch_w, patch_wb, 294912 / 4);
  k_f2b<<<dim3((5308416 / 4 + 255) / 256), dim3(256), 0, stream>>>(qkv_w, qkv_wb, 5308416 / 4);
  k_f2b<<<dim3((1769472 / 4 + 255) / 256), dim3(256), 0, stream>>>(out_w, out_wb, 1769472 / 4);
  k_f2b<<<dim3((7077888 / 4 + 255) / 256), dim3(256), 0, stream>>>(fc1_w, fc1_wb, 7077888 / 4);
  k_f2b<<<dim3((7077888 / 4 + 255) / 256), dim3(256), 0, stream>>>(fc2_w, fc2_wb, 7077888 / 4);

  k_embed_init<<<dim3((BATCH * S_ * D_) / 256), dim3(256), 0, stream>>>(cls_tok, pos_emb, h);
  k_patchify<<<dim3((BATCH * 196 * 768) / 256), dim3(256), 0, stream>>>(x, patches);
  // tok = patches @ patch_w^T + patch_b, accumulated into h (row remap b*196+n -> b*197+1+n)
  k_gemm<2><<<dim3(3, 196), dim3(512), 0, stream>>>(patches, patch_wb, patch_b, nullptr, h, 384, 768, 1);

  for (int i = 0; i < 12; i++) {
    k_ln<<<dim3((unsigned)R), dim3(128), 0, stream>>>(h, ln1_g + i * 384, ln1_b + i * 384, xn);
    // qkv in head-major layout (MODE 3)
    k_gemm<3><<<dim3(9, 197), dim3(512), 0, stream>>>(xn, qkv_wb + (size_t)i * 1152 * 384,
                                                      qkv_b + i * 1152, qkvb, nullptr, 1152, 384, 0);
    k_attn<<<dim3(768), dim3(256), 0, stream>>>(qkvb, ctxb);
    k_gemm<2><<<dim3(3, 197), dim3(512), 0, stream>>>(ctxb, out_wb + (size_t)i * 384 * 384,
                                                      out_b + i * 384, nullptr, h, 384, 384, 0);
    k_ln<<<dim3((unsigned)R), dim3(128), 0, stream>>>(h, ln2_g + i * 384, ln2_b + i * 384, xn);
    k_gemm<1><<<dim3(12, 197), dim3(512), 0, stream>>>(xn, fc1_wb + (size_t)i * 1536 * 384,
                                                       fc1_b + i * 1536, hidb, nullptr, 1536, 384, 0);
    k_gemm<2><<<dim3(3, 197), dim3(512), 0, stream>>>(hidb, fc2_wb + (size_t)i * 384 * 1536,
                                                      fc2_b + i * 384, nullptr, h, 384, 1536, 0);
  }
  k_head<<<dim3(128), dim3(128), 0, stream>>>(h, lnf_g, lnf_b, head_w, out);
}